// Round 11
// baseline (262.233 us; speedup 1.0000x reference)
//
#include <hip/hip_runtime.h>

typedef __bf16 bf16x8 __attribute__((ext_vector_type(8)));
typedef float  f32x4  __attribute__((ext_vector_type(4)));
typedef unsigned short u16x8 __attribute__((ext_vector_type(8)));
typedef unsigned short USHORT;
typedef unsigned int   u32;

__device__ __forceinline__ USHORT f2bf(float f) {
    unsigned u = __float_as_uint(f);
    u += 0x7fffu + ((u >> 16) & 1u);
    return (USHORT)(u >> 16);
}

__device__ __forceinline__ float bf2f(USHORT v) {
    return __uint_as_float((unsigned)v << 16);
}

__device__ __forceinline__ u32 packbf(float lo, float hi) {
    return (u32)f2bf(lo) | ((u32)f2bf(hi) << 16);
}

__device__ __forceinline__ f32x4 fz4() { f32x4 z = {0.f, 0.f, 0.f, 0.f}; return z; }

__device__ __forceinline__ bf16x8 ldbf8(const USHORT* p) { return *(const bf16x8*)p; }

__device__ __forceinline__ f32x4 mfma16(bf16x8 a, bf16x8 b, f32x4 c) {
    return __builtin_amdgcn_mfma_f32_16x16x32_bf16(a, b, c, 0, 0, 0);
}

// async global->LDS, 16B per lane; LDS dest is wave-uniform base + lane*16
__device__ __forceinline__ void gload_lds16(const void* g, void* s) {
    __builtin_amdgcn_global_load_lds(
        (const __attribute__((address_space(1))) unsigned int*)g,
        (__attribute__((address_space(3))) unsigned int*)s, 16, 0, 0);
}

// per-wave LDS ordering fence (epilogue only). sched_barrier per guide rule #18.
__device__ __forceinline__ void lds_fence() {
    asm volatile("s_waitcnt lgkmcnt(0)" ::: "memory");
    __builtin_amdgcn_sched_barrier(0);
}

// ---------------- merged prep: X fp32->bf16 + both W transposes ----------------
__global__ __launch_bounds__(256) void prep_kernel(const float* __restrict__ X,
                                                   const float* __restrict__ Wqkv,
                                                   const float* __restrict__ Wout,
                                                   USHORT* __restrict__ Xb,
                                                   USHORT* __restrict__ Wt1,
                                                   USHORT* __restrict__ Wt3) {
    int bid = blockIdx.x;
    if (bid < 2048) {
        int base = (bid * 256 + threadIdx.x) * 8;
        float4 a = *(const float4*)(X + base);
        float4 b = *(const float4*)(X + base + 4);
        u16x8 o;
        o[0] = f2bf(a.x); o[1] = f2bf(a.y); o[2] = f2bf(a.z); o[3] = f2bf(a.w);
        o[4] = f2bf(b.x); o[5] = f2bf(b.y); o[6] = f2bf(b.z); o[7] = f2bf(b.w);
        *(u16x8*)(Xb + base) = o;
    } else if (bid < 3328) {
        int t = (bid - 2048) * 256 + threadIdx.x;   // 0..327679 : 640x512
        int k = t & 511, n = t >> 9;
        Wt1[t] = f2bf(Wqkv[(size_t)k * 1536 + n]);
    } else {
        int t = (bid - 3328) * 256 + threadIdx.x;   // 0..262143 : 512x512
        int k = t & 511, n = t >> 9;
        Wt3[t] = f2bf(Wout[(size_t)k * 512 + n]);
    }
}

// ---------------- 4-way partial-ctx reduce: o = bf16(sum fp32(parts)) ----------
// In-place safe with o == a (each thread reads its 8 elems before writing them).
__global__ __launch_bounds__(256) void reduce4(const USHORT* __restrict__ a,
                                               const USHORT* __restrict__ b,
                                               const USHORT* __restrict__ c,
                                               const USHORT* __restrict__ d,
                                               USHORT* __restrict__ o) {
    int base = (blockIdx.x * 256 + threadIdx.x) * 8;
    u16x8 va = *(const u16x8*)(a + base);
    u16x8 vb = *(const u16x8*)(b + base);
    u16x8 vc = *(const u16x8*)(c + base);
    u16x8 vd = *(const u16x8*)(d + base);
    u16x8 out;
#pragma unroll
    for (int j = 0; j < 8; ++j)
        out[j] = f2bf(bf2f(va[j]) + bf2f(vb[j]) + bf2f(vc[j]) + bf2f(vd[j]));
    *(u16x8*)(o + base) = out;
}

// ---------------- m97-style bf16 GEMM: C = A(MxK) * Bt(NxK)^T -------------------
template <bool BF16OUT>
__global__ __launch_bounds__(256) void gemm_bt(const USHORT* __restrict__ A,
                                               const USHORT* __restrict__ Bt,
                                               void* __restrict__ Cv,
                                               int M, int N, int K) {
    __shared__ __align__(16) USHORT Asm[128 * 32];
    __shared__ __align__(16) USHORT Bsm[128 * 32];
    const int tid = threadIdx.x;
    const int wv = tid >> 6, ln = tid & 63;
    const int l16 = ln & 15, quad = ln >> 4;
    const int m0 = blockIdx.x * 128, n0 = blockIdx.y * 128;
    const int wm = (wv >> 1) * 64, wn = (wv & 1) * 64;

    f32x4 acc[4][4];
#pragma unroll
    for (int i = 0; i < 4; ++i)
#pragma unroll
        for (int j = 0; j < 4; ++j) acc[i][j] = fz4();

    const int kTiles = K >> 5;
    for (int kt = 0; kt < kTiles; ++kt) {
        __syncthreads();
#pragma unroll
        for (int i = 0; i < 2; ++i) {
            int cb = wv * 128 + i * 64;
            int c = cb + ln;
            gload_lds16(A + (size_t)(m0 + (c >> 2)) * K + kt * 32 + (c & 3) * 8,
                        &Asm[cb * 8]);
            gload_lds16(Bt + (size_t)(n0 + (c >> 2)) * K + kt * 32 + (c & 3) * 8,
                        &Bsm[cb * 8]);
        }
        __syncthreads();

        bf16x8 af[4], bfr[4];
#pragma unroll
        for (int i = 0; i < 4; ++i)
            af[i] = ldbf8(&Asm[(wm + i * 16 + l16) * 32 + quad * 8]);
#pragma unroll
        for (int j = 0; j < 4; ++j)
            bfr[j] = ldbf8(&Bsm[(wn + j * 16 + l16) * 32 + quad * 8]);
#pragma unroll
        for (int i = 0; i < 4; ++i)
#pragma unroll
            for (int j = 0; j < 4; ++j)
                acc[i][j] = mfma16(af[i], bfr[j], acc[i][j]);
    }

#pragma unroll
    for (int i = 0; i < 4; ++i)
#pragma unroll
        for (int j = 0; j < 4; ++j)
#pragma unroll
            for (int r = 0; r < 4; ++r) {
                size_t row = m0 + wm + i * 16 + quad * 4 + r;
                size_t col = n0 + wn + j * 16 + l16;
                if (BF16OUT)
                    ((USHORT*)Cv)[row * N + col] = f2bf(acc[i][j][r]);
                else
                    ((float*)Cv)[row * N + col] = acc[i][j][r];
            }
}

// ---------------- V transpose: Vt[((b*8+h)*64+d)*1024+k] = P[(b*1024+k)*640+(h+2)*64+d]
__global__ __launch_bounds__(256) void transpose_v(const USHORT* __restrict__ P,
                                                   USHORT* __restrict__ Vt) {
    __shared__ __align__(16) USHORT T[64][72];
    const int t = threadIdx.x;
    const int k0 = blockIdx.x * 64;
    const int hh = blockIdx.y;
    const int b = blockIdx.z;
#pragma unroll
    for (int i = 0; i < 2; ++i) {
        int c = i * 256 + t;
        int kk = c >> 3, d8 = (c & 7) * 8;
        u16x8 v = *(const u16x8*)(P + (size_t)((b << 10) + k0 + kk) * 640 +
                                  (hh + 2) * 64 + d8);
        *(u16x8*)&T[kk][d8] = v;
    }
    __syncthreads();
#pragma unroll
    for (int i = 0; i < 2; ++i) {
        int d = (t >> 3) + i * 32;
        int kk0 = (t & 7) * 8;
        u16x8 v;
#pragma unroll
        for (int j = 0; j < 8; ++j) v[j] = T[kk0 + j][d];
        *(u16x8*)(Vt + (size_t)(((b << 3) + hh) * 64 + d) * 1024 + k0 + kk0) = v;
    }
}

// ---------------- fused attention v11 ------------------------------------------
// r10 PMC: 65us, MfmaUtil 10 / VALUBusy 32 / Occupancy 10 (1 wave/SIMD) -> ~58%
// raw latency stall, no TLP. Key fact: VGPR_Count = 220 -- the v10 restructure
// dropped demand BELOW the 256/wave cliff that forced the 4-wave geometry.
// v11 doubles TLP at constant per-wave code:
//   grid 512 x 256-thr blocks, __launch_bounds__(256,2) -> 2 blocks/CU,
//   8 waves/CU = 2 waves/SIMD. kc: 2 -> 4 (256 keys, 8 its) halves per-block
//   work. LDS single-buffered 64KB (2 x 64 = 128 <= 160): the exposed
//   stage->vmcnt-drain serial section is covered by the co-resident block's
//   waves (cross-block TLP replaces the intra-block double buffer).
// Compute phase (swapped scores, per-lane softmax, ds_permute PV, transposed
// epilogue) is byte-identical to v10. reduce2 -> reduce4 (v6-proven).
// XCD grouping: g=bid&31 -> (h,kc); 16 qb-siblings share bid%8 -> one XCD;
// 4 groups/XCD x 512KB unique K/V = 2MB < 4MB L2.
__global__ __launch_bounds__(256, 2) void attn_kernel(const USHORT* __restrict__ P,
                                                      const USHORT* __restrict__ Vt,
                                                      USHORT* __restrict__ pt0,
                                                      USHORT* __restrict__ pt1,
                                                      USHORT* __restrict__ pt2,
                                                      USHORT* __restrict__ pt3) {
    const int bid = blockIdx.x;
    const int g = bid & 31;                       // group (h,kc)
    const int h = g >> 2;
    const int kc = g & 3;                         // 0..3, 256 keys each
    const int qb = bid >> 5;                      // 0..15, 64 q each
    const int tid = threadIdx.x;
    const int wv = tid >> 6;                      // 0..3
    const int lane = tid & 63;
    const int l16 = lane & 15, quad = lane >> 4;
    const int q0 = qb * 64 + wv * 16;

    // Kl chunk map per (b,ks) 2KB region: chunk = half*64+s holds (key=half*16+(s&15), piece=s>>4)
    // Vl chunk map per (b)    4KB region: chunk = dq*32+s    holds (d=dq*16+(s&15),  piece=s>>4)
    __shared__ __align__(16) USHORT Kl[16384];    // 32KB (epilogue scratch after loop)
    __shared__ __align__(16) USHORT Vl[16384];    // 32KB

    // ds_permute dest byte-indices (dest_lane*4), per-lane constants
    const int qhalf = quad >> 1;                  // 0,0,1,1
    const bool qodd = (quad & 1) != 0;
    const bool qhi  = quad >= 2;
    const int idx01 = ((qodd ? (2 + qhalf) : qhalf) * 16 + l16) * 4;
    const int idx23 = ((qodd ? qhalf : (2 + qhalf)) * 16 + l16) * 4;

    // Q fragments: B-layout [n=l16 (q-row)][k=ks*32+quad*8+j] (64 VGPR, held all kernel)
    bf16x8 qf[8][2];
#pragma unroll
    for (int b = 0; b < 8; ++b)
#pragma unroll
        for (int ks = 0; ks < 2; ++ks)
            qf[b][ks] = ldbf8(P + (size_t)((b << 10) + q0 + l16) * 640 + h * 64 +
                              ks * 32 + quad * 8);

    // oacc TRANSPOSED: oacc[b][nt][r] = out[q=l16][d = nt*16 + quad*4 + r]
    f32x4 oacc[8][4];
#pragma unroll
    for (int b = 0; b < 8; ++b)
#pragma unroll
        for (int nt = 0; nt < 4; ++nt) oacc[b][nt] = fz4();

    const int kbase = kc * 256;
    for (int it = 0; it < 8; ++it) {
        const int k0 = kbase + it * 32;

        __syncthreads();  // prev it's LDS reads done; safe to overwrite
        // ---- stage K,V: 64 gload_lds (16/wave); wv<2 -> K, wv>=2 -> V ----
        if (wv < 2) {
#pragma unroll
            for (int i = 0; i < 16; ++i) {
                int gg = wv * 16 + i;             // 0..31
                int b = gg >> 2, ks = (gg >> 1) & 1, half = gg & 1;
                gload_lds16(P + (size_t)((b << 10) + k0 + half * 16 + (lane & 15)) * 640 +
                                (h + 1) * 64 + ks * 32 + (lane >> 4) * 8,
                            &Kl[(b * 2 + ks) * 1024 + half * 512]);
            }
        } else {
#pragma unroll
            for (int i = 0; i < 16; ++i) {
                int gg = (wv - 2) * 16 + i;       // 0..31
                int b = gg >> 2, dq = gg & 3;
                gload_lds16(Vt + (size_t)(((b << 3) + h) * 64 + dq * 16 + (lane & 15)) * 1024 +
                                k0 + (lane >> 4) * 8,
                            &Vl[b * 2048 + dq * 512]);
            }
        }
        __syncthreads();  // drains vmcnt: staged K/V visible (co-resident block computes meanwhile)

        // ---- SWAPPED scores: sacc[b][nt] = P^T tile (lane=q, row=key) ----
        f32x4 sacc[8][2];
#pragma unroll
        for (int b = 0; b < 8; ++b) { sacc[b][0] = fz4(); sacc[b][1] = fz4(); }
#pragma unroll
        for (int ks = 0; ks < 2; ++ks)
#pragma unroll
            for (int nt = 0; nt < 2; ++nt) {
                bf16x8 kf[8];
#pragma unroll
                for (int b = 0; b < 8; ++b)
                    kf[b] = ldbf8(&Kl[(b * 2 + ks) * 1024 + nt * 512 + lane * 8]);
#pragma unroll
                for (int b = 0; b < 8; ++b)
                    sacc[b][nt] = mfma16(kf[b], qf[b][ks], sacc[b][nt]);
            }

        // ---- softmax over batch axis (per-lane), normalize sacc IN PLACE ----
        // scores*scale ~ N(0,0.2^2): exp2 arg |x| < 2 even at 8 sigma.
#pragma unroll
        for (int nt = 0; nt < 2; ++nt)
#pragma unroll
            for (int r = 0; r < 4; ++r) {
                float e[8];
                float Z = 0.f;
#pragma unroll
                for (int b = 0; b < 8; ++b) {
                    // 0.125 (1/sqrt(64)) * log2(e)
                    e[b] = __builtin_amdgcn_exp2f(sacc[b][nt][r] * 0.1803368801f);
                    Z += e[b];
                }
                float inv = __builtin_amdgcn_rcpf(Z);
#pragma unroll
                for (int b = 0; b < 8; ++b)
                    sacc[b][nt][r] = e[b] * inv;
            }

        // ---- PV via ds_permute (no LDS memory, no fences) ----
#pragma unroll
        for (int b = 0; b < 8; ++b) {
            // pack this lane's 8 P^T values (q=l16, keys nt*16+quad*4+r) to bf16
            u32 w00 = packbf(sacc[b][0][0], sacc[b][0][1]);
            u32 w01 = packbf(sacc[b][0][2], sacc[b][0][3]);
            u32 w10 = packbf(sacc[b][1][0], sacc[b][1][1]);
            u32 w11 = packbf(sacc[b][1][2], sacc[b][1][3]);
            // send-side selects (routing verified in v10)
            u32 s0 = qodd ? w10 : w00, s1 = qodd ? w11 : w01;
            u32 s2 = qodd ? w00 : w10, s3 = qodd ? w01 : w11;
            u32 r0 = (u32)__builtin_amdgcn_ds_permute(idx01, (int)s0);
            u32 r1 = (u32)__builtin_amdgcn_ds_permute(idx01, (int)s1);
            u32 r2 = (u32)__builtin_amdgcn_ds_permute(idx23, (int)s2);
            u32 r3 = (u32)__builtin_amdgcn_ds_permute(idx23, (int)s3);
            // receive-side order: lanes quad<2 -> [r0,r1,r2,r3]; quad>=2 -> [r2,r3,r0,r1]
            union { u32 u[4]; bf16x8 v; } pu;
            pu.u[0] = qhi ? r2 : r0;
            pu.u[1] = qhi ? r3 : r1;
            pu.u[2] = qhi ? r0 : r2;
            pu.u[3] = qhi ? r1 : r3;
            bf16x8 pb = pu.v;   // B-layout: n=q=l16, k=key=quad*8+j

            bf16x8 vf[4];
#pragma unroll
            for (int nt = 0; nt < 4; ++nt)
                vf[nt] = ldbf8(&Vl[b * 2048 + nt * 512 + lane * 8]);  // A: m=d, k=key
#pragma unroll
            for (int nt = 0; nt < 4; ++nt)
                oacc[b][nt] = mfma16(vf[nt], pb, oacc[b][nt]);
        }
        // next it's top __syncthreads orders these reads vs. the next stage
    }

    // ---- epilogue: full-128B-line stores via per-wave LDS transpose ----
    // oacc layout: q=l16 (col), d=nt*16+quad*4+r (row) -> ep[q][d] index below.
    __syncthreads();  // all k-loop LDS traffic done; Kl region is dead scratch
    USHORT* part = (kc == 0) ? pt0 : (kc == 1) ? pt1 : (kc == 2) ? pt2 : pt3;
    USHORT* ep = ((USHORT*)Kl) + wv * (16 * 72);  // 4 x 2.25KB <= 32KB
#pragma unroll
    for (int b = 0; b < 8; ++b) {
#pragma unroll
        for (int nt = 0; nt < 4; ++nt)
#pragma unroll
            for (int r = 0; r < 4; ++r)
                ep[l16 * 72 + nt * 16 + quad * 4 + r] = f2bf(oacc[b][nt][r]);
        lds_fence();  // ds_write -> ds_read (wave-private)
#pragma unroll
        for (int half = 0; half < 2; ++half) {
            int row = half * 8 + (lane >> 3);
            int seg = lane & 7;
            u16x8 v = *(const u16x8*)&ep[row * 72 + seg * 8];
            *(u16x8*)(part + (size_t)((b << 10) + q0 + row) * 512 + h * 64 + seg * 8) = v;
        }
        lds_fence();  // WAR: reads drained before next b overwrites tile
    }
}

extern "C" void kernel_launch(void* const* d_in, const int* in_sizes, int n_in,
                              void* d_out, int out_size, void* d_ws, size_t ws_size,
                              hipStream_t stream) {
    const float* X = (const float*)d_in[0];     // (8,1024,512)
    const float* Wqkv = (const float*)d_in[1];  // (512,1536) — only cols 0..639 used
    const float* Wout = (const float*)d_in[2];  // (512,512)
    float* out = (float*)d_out;                 // (8,1024,512) fp32

    char* w = (char*)d_ws;
    USHORT* Xb  = (USHORT*)(w);              //  8,388,608 B (reused as parts[0]/CtxB)
    USHORT* Wt1 = (USHORT*)(w + 8388608);    //    655,360 B  (640x512)
    USHORT* Wt3 = (USHORT*)(w + 9043968);    //    524,288 B  (512x512)
    USHORT* P   = (USHORT*)(w + 9568256);    // 10,485,760 B  (8192x640 bf16)
    USHORT* Vt  = (USHORT*)(w + 20054016);   //  8,388,608 B  (8x8x64x1024 bf16)
    USHORT* pt1 = (USHORT*)(w + 28442624);   //  8,388,608 B  partial ctx (kc=1)
    USHORT* pt2 = (USHORT*)(w + 36831232);   //  8,388,608 B  partial ctx (kc=2)
    USHORT* pt3 = (USHORT*)(w + 45219840);   //  8,388,608 B  partial ctx (kc=3) end=53.6MB
    USHORT* pt0 = Xb;                        // Xb dead after GEMM1; also reduce4 output
    USHORT* CtxB = Xb;

    prep_kernel<<<4352, 256, 0, stream>>>(X, Wqkv, Wout, Xb, Wt1, Wt3);
    // P = Xb @ Wqkv[:, :640]
    gemm_bt<true><<<dim3(64, 5), 256, 0, stream>>>(Xb, Wt1, (void*)P, 8192, 640, 512);
    transpose_v<<<dim3(16, 8, 8), 256, 0, stream>>>(P, Vt);
    attn_kernel<<<512, 256, 0, stream>>>(P, Vt, pt0, pt1, pt2, pt3);
    // CtxB = sum of partials (in-place over pt0, fp32 accumulation)
    reduce4<<<2048, 256, 0, stream>>>(pt0, pt1, pt2, pt3, CtxB);
    // out = ctx @ W_out
    gemm_bt<false><<<dim3(64, 4), 256, 0, stream>>>(CtxB, Wt3, (void*)out, 8192, 512, 512);
}

// Round 12
// 180.255 us; speedup vs baseline: 1.4548x; 1.4548x over previous
//
#include <hip/hip_runtime.h>

typedef __bf16 bf16x8 __attribute__((ext_vector_type(8)));
typedef float  f32x4  __attribute__((ext_vector_type(4)));
typedef unsigned short u16x8 __attribute__((ext_vector_type(8)));
typedef unsigned short USHORT;
typedef unsigned int   u32;

__device__ __forceinline__ USHORT f2bf(float f) {
    unsigned u = __float_as_uint(f);
    u += 0x7fffu + ((u >> 16) & 1u);
    return (USHORT)(u >> 16);
}

__device__ __forceinline__ float bf2f(USHORT v) {
    return __uint_as_float((unsigned)v << 16);
}

// HW packed f32->bf16 (RNE), 2 values in 1 op (T12 recipe; no builtin on gfx950)
__device__ __forceinline__ u32 cvtpk(float lo, float hi) {
    u32 r;
    asm("v_cvt_pk_bf16_f32 %0, %1, %2" : "=v"(r) : "v"(lo), "v"(hi));
    return r;
}

__device__ __forceinline__ f32x4 fz4() { f32x4 z = {0.f, 0.f, 0.f, 0.f}; return z; }

__device__ __forceinline__ bf16x8 ldbf8(const USHORT* p) { return *(const bf16x8*)p; }

__device__ __forceinline__ f32x4 mfma16(bf16x8 a, bf16x8 b, f32x4 c) {
    return __builtin_amdgcn_mfma_f32_16x16x32_bf16(a, b, c, 0, 0, 0);
}

// async global->LDS, 16B per lane; LDS dest is wave-uniform base + lane*16
__device__ __forceinline__ void gload_lds16(const void* g, void* s) {
    __builtin_amdgcn_global_load_lds(
        (const __attribute__((address_space(1))) unsigned int*)g,
        (__attribute__((address_space(3))) unsigned int*)s, 16, 0, 0);
}

// per-wave LDS ordering fence (epilogue only). sched_barrier per guide rule #18.
__device__ __forceinline__ void lds_fence() {
    asm volatile("s_waitcnt lgkmcnt(0)" ::: "memory");
    __builtin_amdgcn_sched_barrier(0);
}

// ---------------- merged prep: X fp32->bf16 + both W transposes ----------------
__global__ __launch_bounds__(256) void prep_kernel(const float* __restrict__ X,
                                                   const float* __restrict__ Wqkv,
                                                   const float* __restrict__ Wout,
                                                   USHORT* __restrict__ Xb,
                                                   USHORT* __restrict__ Wt1,
                                                   USHORT* __restrict__ Wt3) {
    int bid = blockIdx.x;
    if (bid < 2048) {
        int base = (bid * 256 + threadIdx.x) * 8;
        float4 a = *(const float4*)(X + base);
        float4 b = *(const float4*)(X + base + 4);
        u16x8 o;
        o[0] = f2bf(a.x); o[1] = f2bf(a.y); o[2] = f2bf(a.z); o[3] = f2bf(a.w);
        o[4] = f2bf(b.x); o[5] = f2bf(b.y); o[6] = f2bf(b.z); o[7] = f2bf(b.w);
        *(u16x8*)(Xb + base) = o;
    } else if (bid < 3328) {
        int t = (bid - 2048) * 256 + threadIdx.x;   // 0..327679 : 640x512
        int k = t & 511, n = t >> 9;
        Wt1[t] = f2bf(Wqkv[(size_t)k * 1536 + n]);
    } else {
        int t = (bid - 3328) * 256 + threadIdx.x;   // 0..262143 : 512x512
        int k = t & 511, n = t >> 9;
        Wt3[t] = f2bf(Wout[(size_t)k * 512 + n]);
    }
}

// ---------------- 2-way partial-ctx reduce: o = bf16(f32(a)+f32(b)) ------------
// In-place safe with o == a (each thread reads its 8 elems before writing them).
__global__ __launch_bounds__(256) void reduce2(const USHORT* __restrict__ a,
                                               const USHORT* __restrict__ b,
                                               USHORT* __restrict__ o) {
    int base = (blockIdx.x * 256 + threadIdx.x) * 8;
    u16x8 va = *(const u16x8*)(a + base);
    u16x8 vb = *(const u16x8*)(b + base);
    u16x8 out;
#pragma unroll
    for (int j = 0; j < 8; ++j)
        out[j] = f2bf(bf2f(va[j]) + bf2f(vb[j]));
    *(u16x8*)(o + base) = out;
}

// ---------------- m97-style bf16 GEMM: C = A(MxK) * Bt(NxK)^T -------------------
template <bool BF16OUT>
__global__ __launch_bounds__(256) void gemm_bt(const USHORT* __restrict__ A,
                                               const USHORT* __restrict__ Bt,
                                               void* __restrict__ Cv,
                                               int M, int N, int K) {
    __shared__ __align__(16) USHORT Asm[128 * 32];
    __shared__ __align__(16) USHORT Bsm[128 * 32];
    const int tid = threadIdx.x;
    const int wv = tid >> 6, ln = tid & 63;
    const int l16 = ln & 15, quad = ln >> 4;
    const int m0 = blockIdx.x * 128, n0 = blockIdx.y * 128;
    const int wm = (wv >> 1) * 64, wn = (wv & 1) * 64;

    f32x4 acc[4][4];
#pragma unroll
    for (int i = 0; i < 4; ++i)
#pragma unroll
        for (int j = 0; j < 4; ++j) acc[i][j] = fz4();

    const int kTiles = K >> 5;
    for (int kt = 0; kt < kTiles; ++kt) {
        __syncthreads();
#pragma unroll
        for (int i = 0; i < 2; ++i) {
            int cb = wv * 128 + i * 64;
            int c = cb + ln;
            gload_lds16(A + (size_t)(m0 + (c >> 2)) * K + kt * 32 + (c & 3) * 8,
                        &Asm[cb * 8]);
            gload_lds16(Bt + (size_t)(n0 + (c >> 2)) * K + kt * 32 + (c & 3) * 8,
                        &Bsm[cb * 8]);
        }
        __syncthreads();

        bf16x8 af[4], bfr[4];
#pragma unroll
        for (int i = 0; i < 4; ++i)
            af[i] = ldbf8(&Asm[(wm + i * 16 + l16) * 32 + quad * 8]);
#pragma unroll
        for (int j = 0; j < 4; ++j)
            bfr[j] = ldbf8(&Bsm[(wn + j * 16 + l16) * 32 + quad * 8]);
#pragma unroll
        for (int i = 0; i < 4; ++i)
#pragma unroll
            for (int j = 0; j < 4; ++j)
                acc[i][j] = mfma16(af[i], bfr[j], acc[i][j]);
    }

#pragma unroll
    for (int i = 0; i < 4; ++i)
#pragma unroll
        for (int j = 0; j < 4; ++j)
#pragma unroll
            for (int r = 0; r < 4; ++r) {
                size_t row = m0 + wm + i * 16 + quad * 4 + r;
                size_t col = n0 + wn + j * 16 + l16;
                if (BF16OUT)
                    ((USHORT*)Cv)[row * N + col] = f2bf(acc[i][j][r]);
                else
                    ((float*)Cv)[row * N + col] = acc[i][j][r];
            }
}

// ---------------- V transpose: Vt[((b*8+h)*64+d)*1024+k] = P[(b*1024+k)*640+(h+2)*64+d]
__global__ __launch_bounds__(256) void transpose_v(const USHORT* __restrict__ P,
                                                   USHORT* __restrict__ Vt) {
    __shared__ __align__(16) USHORT T[64][72];
    const int t = threadIdx.x;
    const int k0 = blockIdx.x * 64;
    const int hh = blockIdx.y;
    const int b = blockIdx.z;
#pragma unroll
    for (int i = 0; i < 2; ++i) {
        int c = i * 256 + t;
        int kk = c >> 3, d8 = (c & 7) * 8;
        u16x8 v = *(const u16x8*)(P + (size_t)((b << 10) + k0 + kk) * 640 +
                                  (hh + 2) * 64 + d8);
        *(u16x8*)&T[kk][d8] = v;
    }
    __syncthreads();
#pragma unroll
    for (int i = 0; i < 2; ++i) {
        int d = (t >> 3) + i * 32;
        int kk0 = (t & 7) * 8;
        u16x8 v;
#pragma unroll
        for (int j = 0; j < 8; ++j) v[j] = T[kk0 + j][d];
        *(u16x8*)(Vt + (size_t)(((b << 3) + hh) * 64 + d) * 1024 + k0 + kk0) = v;
    }
}

// ---------------- fused attention v12 ------------------------------------------
// r11 post-mortem: VGPR_Count=220 (r10) was ARCH-only; oacc's 128 AGPRs put true
// demand ~348 -> the (256,2) cap of 256 forced ~90 spilled regs (WRITE 259MB).
// 2 waves/SIMD is impossible at 16q x 64d x 8batch per wave.
// v12 halves the per-wave BATCH count instead of dieting:
//   wave = 16q x 64d x 4 batches: oacc 64(acc) + qf 32 + sacc 32 + kf 16 +
//   temps ~60 -> ~205 unified regs < 256 cap. Fits with margin.
//   Softmax over the batch axis needs the other 4 batches: paired wave (wv^1,
//   same q-tile, other batch-half) exchanges per-position partial-Z through an
//   8KB LDS buffer (2 b128 writes -> barrier -> 2 b128 reads -> add -> rcp).
//   Chip-wide MFMA/VALU work unchanged (no duplication).
// Geometry: grid 512 x 256thr, __launch_bounds__(256,2) -> 2 blocks/CU,
//   2 waves/SIMD. Block = 2 q-tiles x 2 batch-halves, 512 keys (kc=2, 16 its).
//   LDS 72KB (Kl 32 + Vl 32 single-buffer + zex 8); 144KB/CU <= 160.
//   Stage->drain exposure covered by the co-resident block (cross-block TLP).
// VALU cut (r10 profile: VALUBusy 32% dominated by manual f2bf packing):
//   PV pack now uses v_cvt_pk_bf16_f32 (4 ops/batch vs ~36).
// Scores (swapped mfma(K,Q)), ds_permute PV routing, transposed full-line
// epilogue: byte-identical to v10's verified code, restricted to 4 batches.
__global__ __launch_bounds__(256, 2) void attn_kernel(const USHORT* __restrict__ P,
                                                      const USHORT* __restrict__ Vt,
                                                      USHORT* __restrict__ pt0,
                                                      USHORT* __restrict__ pt1) {
    const int bid = blockIdx.x;
    const int g = bid & 15;                       // group (h,kc)
    const int h = g >> 1;
    const int kc = g & 1;                         // 0..1, 512 keys each
    const int qb = bid >> 4;                      // 0..31, 32 q each
    const int tid = threadIdx.x;
    const int wv = tid >> 6;                      // 0..3
    const int qt = wv >> 1;                       // q-tile within block
    const int bhalf = wv & 1;                     // batch-half: batches bhalf*4..+3
    const int lane = tid & 63;
    const int l16 = lane & 15, quad = lane >> 4;
    const int q0 = qb * 32 + qt * 16;

    // Kl chunk map per (b,ks) 2KB region: chunk = half*64+s holds (key=half*16+(s&15), piece=s>>4)
    // Vl chunk map per (b)    4KB region: chunk = dq*32+s    holds (d=dq*16+(s&15),  piece=s>>4)
    __shared__ __align__(16) USHORT Kl[16384];    // 32KB (epilogue scratch after loop)
    __shared__ __align__(16) USHORT Vl[16384];    // 32KB
    __shared__ __align__(16) float  zex[4][64][8]; // 8KB: partial-Z exchange

    // ds_permute dest byte-indices (dest_lane*4), per-lane constants (v10-verified)
    const int qhalf = quad >> 1;                  // 0,0,1,1
    const bool qodd = (quad & 1) != 0;
    const bool qhi  = quad >= 2;
    const int idx01 = ((qodd ? (2 + qhalf) : qhalf) * 16 + l16) * 4;
    const int idx23 = ((qodd ? qhalf : (2 + qhalf)) * 16 + l16) * 4;

    // Q fragments: B-layout [n=l16 (q-row)][k=ks*32+quad*8+j], 4 batches (32 VGPR)
    bf16x8 qf[4][2];
#pragma unroll
    for (int b = 0; b < 4; ++b)
#pragma unroll
        for (int ks = 0; ks < 2; ++ks)
            qf[b][ks] = ldbf8(P + (size_t)(((bhalf * 4 + b) << 10) + q0 + l16) * 640 +
                              h * 64 + ks * 32 + quad * 8);

    // oacc TRANSPOSED: oacc[b][nt][r] = out[q=l16][d = nt*16 + quad*4 + r]  (64 acc)
    f32x4 oacc[4][4];
#pragma unroll
    for (int b = 0; b < 4; ++b)
#pragma unroll
        for (int nt = 0; nt < 4; ++nt) oacc[b][nt] = fz4();

    const int kbase = kc * 512;
    for (int it = 0; it < 16; ++it) {
        const int k0 = kbase + it * 32;

        __syncthreads();  // prev it's LDS reads done; safe to overwrite
        // ---- stage K,V (ALL 8 batches; both halves share): 64 gload_lds ----
        if (wv < 2) {
#pragma unroll
            for (int i = 0; i < 16; ++i) {
                int gg = wv * 16 + i;             // 0..31
                int b = gg >> 2, ks = (gg >> 1) & 1, half = gg & 1;
                gload_lds16(P + (size_t)((b << 10) + k0 + half * 16 + (lane & 15)) * 640 +
                                (h + 1) * 64 + ks * 32 + (lane >> 4) * 8,
                            &Kl[(b * 2 + ks) * 1024 + half * 512]);
            }
        } else {
#pragma unroll
            for (int i = 0; i < 16; ++i) {
                int gg = (wv - 2) * 16 + i;       // 0..31
                int b = gg >> 2, dq = gg & 3;
                gload_lds16(Vt + (size_t)(((b << 3) + h) * 64 + dq * 16 + (lane & 15)) * 1024 +
                                k0 + (lane >> 4) * 8,
                            &Vl[b * 2048 + dq * 512]);
            }
        }
        __syncthreads();  // drains vmcnt (co-resident block computes meanwhile)

        // ---- SWAPPED scores, 4 batches: sacc = P^T tile (lane=q, row=key) ----
        f32x4 sacc[4][2];
#pragma unroll
        for (int b = 0; b < 4; ++b) { sacc[b][0] = fz4(); sacc[b][1] = fz4(); }
#pragma unroll
        for (int ks = 0; ks < 2; ++ks)
#pragma unroll
            for (int nt = 0; nt < 2; ++nt) {
                bf16x8 kf[4];
#pragma unroll
                for (int b = 0; b < 4; ++b)
                    kf[b] = ldbf8(&Kl[((bhalf * 4 + b) * 2 + ks) * 1024 + nt * 512 + lane * 8]);
#pragma unroll
                for (int b = 0; b < 4; ++b)
                    sacc[b][nt] = mfma16(kf[b], qf[b][ks], sacc[b][nt]);
            }

        // ---- softmax over batch axis: exp + partial Z, cross-wave exchange ----
        // scores*scale ~ N(0,0.2^2): exp2 arg |x| < 2 even at 8 sigma.
        f32x4 zh[2];
#pragma unroll
        for (int nt = 0; nt < 2; ++nt)
#pragma unroll
            for (int r = 0; r < 4; ++r) {
                float z = 0.f;
#pragma unroll
                for (int b = 0; b < 4; ++b) {
                    // 0.125 (1/sqrt(64)) * log2(e)
                    float e = __builtin_amdgcn_exp2f(sacc[b][nt][r] * 0.1803368801f);
                    sacc[b][nt][r] = e;           // keep e in place
                    z += e;
                }
                zh[nt][r] = z;
            }
        *(f32x4*)&zex[wv][lane][0] = zh[0];
        *(f32x4*)&zex[wv][lane][4] = zh[1];
        __syncthreads();                          // publish partial Z to partner
        f32x4 zp0 = *(const f32x4*)&zex[wv ^ 1][lane][0];
        f32x4 zp1 = *(const f32x4*)&zex[wv ^ 1][lane][4];
#pragma unroll
        for (int nt = 0; nt < 2; ++nt)
#pragma unroll
            for (int r = 0; r < 4; ++r) {
                float inv = __builtin_amdgcn_rcpf(zh[nt][r] + (nt ? zp1[r] : zp0[r]));
#pragma unroll
                for (int b = 0; b < 4; ++b)
                    sacc[b][nt][r] *= inv;
            }

        // ---- PV via ds_permute (cvt_pk pack; routing v10-verified) ----
#pragma unroll
        for (int b = 0; b < 4; ++b) {
            u32 w00 = cvtpk(sacc[b][0][0], sacc[b][0][1]);
            u32 w01 = cvtpk(sacc[b][0][2], sacc[b][0][3]);
            u32 w10 = cvtpk(sacc[b][1][0], sacc[b][1][1]);
            u32 w11 = cvtpk(sacc[b][1][2], sacc[b][1][3]);
            u32 s0 = qodd ? w10 : w00, s1 = qodd ? w11 : w01;
            u32 s2 = qodd ? w00 : w10, s3 = qodd ? w01 : w11;
            u32 r0 = (u32)__builtin_amdgcn_ds_permute(idx01, (int)s0);
            u32 r1 = (u32)__builtin_amdgcn_ds_permute(idx01, (int)s1);
            u32 r2 = (u32)__builtin_amdgcn_ds_permute(idx23, (int)s2);
            u32 r3 = (u32)__builtin_amdgcn_ds_permute(idx23, (int)s3);
            union { u32 u[4]; bf16x8 v; } pu;
            pu.u[0] = qhi ? r2 : r0;
            pu.u[1] = qhi ? r3 : r1;
            pu.u[2] = qhi ? r0 : r2;
            pu.u[3] = qhi ? r1 : r3;
            bf16x8 pb = pu.v;   // B-layout: n=q=l16, k=key=quad*8+j

            bf16x8 vf[4];
#pragma unroll
            for (int nt = 0; nt < 4; ++nt)
                vf[nt] = ldbf8(&Vl[(bhalf * 4 + b) * 2048 + nt * 512 + lane * 8]);
#pragma unroll
            for (int nt = 0; nt < 4; ++nt)
                oacc[b][nt] = mfma16(vf[nt], pb, oacc[b][nt]);
        }
        // next it's top __syncthreads orders these reads vs. the next stage
    }

    // ---- epilogue: full-128B-line stores via per-wave LDS transpose ----
    // oacc layout: q=l16 (col), d=nt*16+quad*4+r (row) -> ep[q][d] index below.
    __syncthreads();  // all k-loop LDS traffic done; Kl region is dead scratch
    USHORT* part = kc ? pt1 : pt0;
    USHORT* ep = ((USHORT*)Kl) + wv * (16 * 72);  // 4 x 2.25KB <= 32KB
#pragma unroll
    for (int b = 0; b < 4; ++b) {
        const int bs = bhalf * 4 + b;
#pragma unroll
        for (int nt = 0; nt < 4; ++nt)
#pragma unroll
            for (int r = 0; r < 4; ++r)
                ep[l16 * 72 + nt * 16 + quad * 4 + r] = f2bf(oacc[b][nt][r]);
        lds_fence();  // ds_write -> ds_read (wave-private)
#pragma unroll
        for (int half = 0; half < 2; ++half) {
            int row = half * 8 + (lane >> 3);
            int seg = lane & 7;
            u16x8 v = *(const u16x8*)&ep[row * 72 + seg * 8];
            *(u16x8*)(part + (size_t)((bs << 10) + q0 + row) * 512 + h * 64 + seg * 8) = v;
        }
        lds_fence();  // WAR: reads drained before next b overwrites tile
    }
}

extern "C" void kernel_launch(void* const* d_in, const int* in_sizes, int n_in,
                              void* d_out, int out_size, void* d_ws, size_t ws_size,
                              hipStream_t stream) {
    const float* X = (const float*)d_in[0];     // (8,1024,512)
    const float* Wqkv = (const float*)d_in[1];  // (512,1536) — only cols 0..639 used
    const float* Wout = (const float*)d_in[2];  // (512,512)
    float* out = (float*)d_out;                 // (8,1024,512) fp32

    char* w = (char*)d_ws;
    USHORT* Xb  = (USHORT*)(w);              //  8,388,608 B (reused as parts[0]/CtxB)
    USHORT* Wt1 = (USHORT*)(w + 8388608);    //    655,360 B  (640x512)
    USHORT* Wt3 = (USHORT*)(w + 9043968);    //    524,288 B  (512x512)
    USHORT* P   = (USHORT*)(w + 9568256);    // 10,485,760 B  (8192x640 bf16)
    USHORT* Vt  = (USHORT*)(w + 20054016);   //  8,388,608 B  (8x8x64x1024 bf16)
    USHORT* pt1 = (USHORT*)(w + 28442624);   //  8,388,608 B  partial ctx (kc=1)
    USHORT* pt0 = Xb;                        // Xb dead after GEMM1; also reduce2 output
    USHORT* CtxB = Xb;

    prep_kernel<<<4352, 256, 0, stream>>>(X, Wqkv, Wout, Xb, Wt1, Wt3);
    // P = Xb @ Wqkv[:, :640]
    gemm_bt<true><<<dim3(64, 5), 256, 0, stream>>>(Xb, Wt1, (void*)P, 8192, 640, 512);
    transpose_v<<<dim3(16, 8, 8), 256, 0, stream>>>(P, Vt);
    attn_kernel<<<512, 256, 0, stream>>>(P, Vt, pt0, pt1);
    // CtxB = pt0 + pt1 (in-place over pt0, fp32 accumulation)
    reduce2<<<2048, 256, 0, stream>>>(pt0, pt1, CtxB);
    // out = ctx @ W_out
    gemm_bt<false><<<dim3(64, 4), 256, 0, stream>>>(CtxB, Wt3, (void*)out, 8192, 512, 512);
}

// Round 13
// 174.120 us; speedup vs baseline: 1.5060x; 1.0352x over previous
//
#include <hip/hip_runtime.h>

typedef __bf16 bf16x8 __attribute__((ext_vector_type(8)));
typedef float  f32x4  __attribute__((ext_vector_type(4)));
typedef unsigned short u16x8 __attribute__((ext_vector_type(8)));
typedef unsigned short USHORT;
typedef unsigned int   u32;

__device__ __forceinline__ USHORT f2bf(float f) {
    unsigned u = __float_as_uint(f);
    u += 0x7fffu + ((u >> 16) & 1u);
    return (USHORT)(u >> 16);
}

__device__ __forceinline__ float bf2f(USHORT v) {
    return __uint_as_float((unsigned)v << 16);
}

// HW packed f32->bf16 (RNE), 2 values in 1 op (T12 recipe; no builtin on gfx950)
__device__ __forceinline__ u32 cvtpk(float lo, float hi) {
    u32 r;
    asm("v_cvt_pk_bf16_f32 %0, %1, %2" : "=v"(r) : "v"(lo), "v"(hi));
    return r;
}

__device__ __forceinline__ f32x4 fz4() { f32x4 z = {0.f, 0.f, 0.f, 0.f}; return z; }

__device__ __forceinline__ bf16x8 ldbf8(const USHORT* p) { return *(const bf16x8*)p; }

__device__ __forceinline__ f32x4 mfma16(bf16x8 a, bf16x8 b, f32x4 c) {
    return __builtin_amdgcn_mfma_f32_16x16x32_bf16(a, b, c, 0, 0, 0);
}

// async global->LDS, 16B per lane; LDS dest is wave-uniform base + lane*16
__device__ __forceinline__ void gload_lds16(const void* g, void* s) {
    __builtin_amdgcn_global_load_lds(
        (const __attribute__((address_space(1))) unsigned int*)g,
        (__attribute__((address_space(3))) unsigned int*)s, 16, 0, 0);
}

// per-wave LDS ordering fence (epilogue only). sched_barrier per guide rule #18.
__device__ __forceinline__ void lds_fence() {
    asm volatile("s_waitcnt lgkmcnt(0)" ::: "memory");
    __builtin_amdgcn_sched_barrier(0);
}

// ---------------- merged prep: X fp32->bf16 + both W transposes ----------------
__global__ __launch_bounds__(256) void prep_kernel(const float* __restrict__ X,
                                                   const float* __restrict__ Wqkv,
                                                   const float* __restrict__ Wout,
                                                   USHORT* __restrict__ Xb,
                                                   USHORT* __restrict__ Wt1,
                                                   USHORT* __restrict__ Wt3) {
    int bid = blockIdx.x;
    if (bid < 2048) {
        int base = (bid * 256 + threadIdx.x) * 8;
        float4 a = *(const float4*)(X + base);
        float4 b = *(const float4*)(X + base + 4);
        u16x8 o;
        o[0] = f2bf(a.x); o[1] = f2bf(a.y); o[2] = f2bf(a.z); o[3] = f2bf(a.w);
        o[4] = f2bf(b.x); o[5] = f2bf(b.y); o[6] = f2bf(b.z); o[7] = f2bf(b.w);
        *(u16x8*)(Xb + base) = o;
    } else if (bid < 3328) {
        int t = (bid - 2048) * 256 + threadIdx.x;   // 0..327679 : 640x512
        int k = t & 511, n = t >> 9;
        Wt1[t] = f2bf(Wqkv[(size_t)k * 1536 + n]);
    } else {
        int t = (bid - 3328) * 256 + threadIdx.x;   // 0..262143 : 512x512
        int k = t & 511, n = t >> 9;
        Wt3[t] = f2bf(Wout[(size_t)k * 512 + n]);
    }
}

// ---------------- m97-style bf16 GEMM: C = A(MxK) * Bt(NxK)^T -------------------
template <bool BF16OUT>
__global__ __launch_bounds__(256) void gemm_bt(const USHORT* __restrict__ A,
                                               const USHORT* __restrict__ Bt,
                                               void* __restrict__ Cv,
                                               int M, int N, int K) {
    __shared__ __align__(16) USHORT Asm[128 * 32];
    __shared__ __align__(16) USHORT Bsm[128 * 32];
    const int tid = threadIdx.x;
    const int wv = tid >> 6, ln = tid & 63;
    const int l16 = ln & 15, quad = ln >> 4;
    const int m0 = blockIdx.x * 128, n0 = blockIdx.y * 128;
    const int wm = (wv >> 1) * 64, wn = (wv & 1) * 64;

    f32x4 acc[4][4];
#pragma unroll
    for (int i = 0; i < 4; ++i)
#pragma unroll
        for (int j = 0; j < 4; ++j) acc[i][j] = fz4();

    const int kTiles = K >> 5;
    for (int kt = 0; kt < kTiles; ++kt) {
        __syncthreads();
#pragma unroll
        for (int i = 0; i < 2; ++i) {
            int cb = wv * 128 + i * 64;
            int c = cb + ln;
            gload_lds16(A + (size_t)(m0 + (c >> 2)) * K + kt * 32 + (c & 3) * 8,
                        &Asm[cb * 8]);
            gload_lds16(Bt + (size_t)(n0 + (c >> 2)) * K + kt * 32 + (c & 3) * 8,
                        &Bsm[cb * 8]);
        }
        __syncthreads();

        bf16x8 af[4], bfr[4];
#pragma unroll
        for (int i = 0; i < 4; ++i)
            af[i] = ldbf8(&Asm[(wm + i * 16 + l16) * 32 + quad * 8]);
#pragma unroll
        for (int j = 0; j < 4; ++j)
            bfr[j] = ldbf8(&Bsm[(wn + j * 16 + l16) * 32 + quad * 8]);
#pragma unroll
        for (int i = 0; i < 4; ++i)
#pragma unroll
            for (int j = 0; j < 4; ++j)
                acc[i][j] = mfma16(af[i], bfr[j], acc[i][j]);
    }

#pragma unroll
    for (int i = 0; i < 4; ++i)
#pragma unroll
        for (int j = 0; j < 4; ++j)
#pragma unroll
            for (int r = 0; r < 4; ++r) {
                size_t row = m0 + wm + i * 16 + quad * 4 + r;
                size_t col = n0 + wn + j * 16 + l16;
                if (BF16OUT)
                    ((USHORT*)Cv)[row * N + col] = f2bf(acc[i][j][r]);
                else
                    ((float*)Cv)[row * N + col] = acc[i][j][r];
            }
}

// ------- GEMM2 with fused 2-way partial sum: C = (A0+A1)(MxK) * Bt(NxK)^T -------
// A is reg-staged (load both partials, fp32 add, cvt_pk, ds_write_b128 linear ->
// conflict-free); B keeps the proven global_load_lds path. Replaces the reduce2
// kernel entirely (one less launch, -25MB of reduce traffic).
__global__ __launch_bounds__(256) void gemm_bt_sum2(const USHORT* __restrict__ A0,
                                                    const USHORT* __restrict__ A1,
                                                    const USHORT* __restrict__ Bt,
                                                    float* __restrict__ C,
                                                    int M, int N, int K) {
    __shared__ __align__(16) USHORT Asm[128 * 32];
    __shared__ __align__(16) USHORT Bsm[128 * 32];
    const int tid = threadIdx.x;
    const int wv = tid >> 6, ln = tid & 63;
    const int l16 = ln & 15, quad = ln >> 4;
    const int m0 = blockIdx.x * 128, n0 = blockIdx.y * 128;
    const int wm = (wv >> 1) * 64, wn = (wv & 1) * 64;

    f32x4 acc[4][4];
#pragma unroll
    for (int i = 0; i < 4; ++i)
#pragma unroll
        for (int j = 0; j < 4; ++j) acc[i][j] = fz4();

    const int kTiles = K >> 5;
    for (int kt = 0; kt < kTiles; ++kt) {
        __syncthreads();  // Asm WAR (prev reads done) + Bsm reuse
#pragma unroll
        for (int i = 0; i < 2; ++i) {
            int cb = wv * 128 + i * 64;
            int c = cb + ln;
            size_t aoff = (size_t)(m0 + (c >> 2)) * K + kt * 32 + (c & 3) * 8;
            u16x8 a0 = *(const u16x8*)(A0 + aoff);
            u16x8 a1 = *(const u16x8*)(A1 + aoff);
            union { u32 u[4]; u16x8 v; } s;
#pragma unroll
            for (int j = 0; j < 4; ++j)
                s.u[j] = cvtpk(bf2f(a0[2 * j]) + bf2f(a1[2 * j]),
                               bf2f(a0[2 * j + 1]) + bf2f(a1[2 * j + 1]));
            *(u16x8*)&Asm[c * 8] = s.v;   // linear 16B per lane: conflict-free
            gload_lds16(Bt + (size_t)(n0 + (c >> 2)) * K + kt * 32 + (c & 3) * 8,
                        &Bsm[cb * 8]);
        }
        __syncthreads();  // drains lgkm (Asm ds_writes) + vmcnt (Bsm DMA)

        bf16x8 af[4], bfr[4];
#pragma unroll
        for (int i = 0; i < 4; ++i)
            af[i] = ldbf8(&Asm[(wm + i * 16 + l16) * 32 + quad * 8]);
#pragma unroll
        for (int j = 0; j < 4; ++j)
            bfr[j] = ldbf8(&Bsm[(wn + j * 16 + l16) * 32 + quad * 8]);
#pragma unroll
        for (int i = 0; i < 4; ++i)
#pragma unroll
            for (int j = 0; j < 4; ++j)
                acc[i][j] = mfma16(af[i], bfr[j], acc[i][j]);
    }

#pragma unroll
    for (int i = 0; i < 4; ++i)
#pragma unroll
        for (int j = 0; j < 4; ++j)
#pragma unroll
            for (int r = 0; r < 4; ++r) {
                size_t row = m0 + wm + i * 16 + quad * 4 + r;
                size_t col = n0 + wn + j * 16 + l16;
                C[row * N + col] = acc[i][j][r];
            }
}

// ---------------- V transpose: Vt[((b*8+h)*64+d)*1024+k] = P[(b*1024+k)*640+(h+2)*64+d]
__global__ __launch_bounds__(256) void transpose_v(const USHORT* __restrict__ P,
                                                   USHORT* __restrict__ Vt) {
    __shared__ __align__(16) USHORT T[64][72];
    const int t = threadIdx.x;
    const int k0 = blockIdx.x * 64;
    const int hh = blockIdx.y;
    const int b = blockIdx.z;
#pragma unroll
    for (int i = 0; i < 2; ++i) {
        int c = i * 256 + t;
        int kk = c >> 3, d8 = (c & 7) * 8;
        u16x8 v = *(const u16x8*)(P + (size_t)((b << 10) + k0 + kk) * 640 +
                                  (hh + 2) * 64 + d8);
        *(u16x8*)&T[kk][d8] = v;
    }
    __syncthreads();
#pragma unroll
    for (int i = 0; i < 2; ++i) {
        int d = (t >> 3) + i * 32;
        int kk0 = (t & 7) * 8;
        u16x8 v;
#pragma unroll
        for (int j = 0; j < 8; ++j) v[j] = T[kk0 + j][d];
        *(u16x8*)(Vt + (size_t)(((b << 3) + hh) * 64 + d) * 1024 + k0 + kk0) = v;
    }
}

// ---------------- fused attention v13 = v10 (proven 65us) + cvt_pk pack --------
// r12 post-mortem: v12's 2-waves/SIMD experiment was confounded (single-buffer
// exposed the stage drain, zex barrier added coupling, 4-batch halved ILP) and
// regressed. v13 reverts to the PROVEN v10 structure: 256 blocks x 4 waves,
// 1 block/CU (512 regs/wave, no spills), double-buffered K/V staging,
// swapped-operand scores (mfma(K,Q) -> P^T, lane=q), per-lane batch-axis
// softmax, ds_permute PV (no LDS round-trip, no fences in loop).
// Single delta vs v10: PV pack uses v_cvt_pk_bf16_f32 (4 ops/batch, validated
// numerically in r12) instead of ~28 manual f2bf ops -> cuts the 32%-busy VALU.
__global__ __launch_bounds__(256, 1) void attn_kernel(const USHORT* __restrict__ P,
                                                      const USHORT* __restrict__ Vt,
                                                      USHORT* __restrict__ pt0,
                                                      USHORT* __restrict__ pt1) {
    const int bid = blockIdx.x;
    const int g = bid & 15;                       // group (h,kc)
    const int h = g >> 1;
    const int kc = g & 1;                         // 0..1, 512 keys each
    const int qb = bid >> 4;                      // 0..15, 64 q each
    const int tid = threadIdx.x;
    const int wv = tid >> 6;                      // 0..3
    const int lane = tid & 63;
    const int l16 = lane & 15, quad = lane >> 4;
    const int q0 = qb * 64 + wv * 16;

    // Kl chunk map per (b,ks) 2KB region: chunk = half*64+s holds (key=half*16+(s&15), piece=s>>4)
    // Vl chunk map per (b)    4KB region: chunk = dq*32+s    holds (d=dq*16+(s&15),  piece=s>>4)
    __shared__ __align__(16) USHORT Kl[2][16384];   // 64KB (buf0 = epilogue scratch after loop)
    __shared__ __align__(16) USHORT Vl[2][16384];   // 64KB

    // ds_permute dest byte-indices (dest_lane*4), per-lane constants (v10-verified)
    const int qhalf = quad >> 1;                  // 0,0,1,1
    const bool qodd = (quad & 1) != 0;
    const bool qhi  = quad >= 2;
    const int idx01 = ((qodd ? (2 + qhalf) : qhalf) * 16 + l16) * 4;
    const int idx23 = ((qodd ? qhalf : (2 + qhalf)) * 16 + l16) * 4;

    // Q fragments: B-layout [n=l16 (q-row)][k=ks*32+quad*8+j] (64 VGPR, held all kernel)
    bf16x8 qf[8][2];
#pragma unroll
    for (int b = 0; b < 8; ++b)
#pragma unroll
        for (int ks = 0; ks < 2; ++ks)
            qf[b][ks] = ldbf8(P + (size_t)((b << 10) + q0 + l16) * 640 + h * 64 +
                              ks * 32 + quad * 8);

    // oacc TRANSPOSED: oacc[b][nt][r] = out[q=l16][d = nt*16 + quad*4 + r]
    f32x4 oacc[8][4];
#pragma unroll
    for (int b = 0; b < 8; ++b)
#pragma unroll
        for (int nt = 0; nt < 4; ++nt) oacc[b][nt] = fz4();

    // ---- staging: 64 gload_lds per it (16/wave); wv<2 -> K, wv>=2 -> V ----
    auto stage = [&](int k0s, int buf) {
        if (wv < 2) {
#pragma unroll
            for (int i = 0; i < 16; ++i) {
                int gg = wv * 16 + i;             // 0..31
                int b = gg >> 2, ks = (gg >> 1) & 1, half = gg & 1;
                gload_lds16(P + (size_t)((b << 10) + k0s + half * 16 + (lane & 15)) * 640 +
                                (h + 1) * 64 + ks * 32 + (lane >> 4) * 8,
                            &Kl[buf][(b * 2 + ks) * 1024 + half * 512]);
            }
        } else {
#pragma unroll
            for (int i = 0; i < 16; ++i) {
                int gg = (wv - 2) * 16 + i;       // 0..31
                int b = gg >> 2, dq = gg & 3;
                gload_lds16(Vt + (size_t)(((b << 3) + h) * 64 + dq * 16 + (lane & 15)) * 1024 +
                                k0s + (lane >> 4) * 8,
                            &Vl[buf][b * 2048 + dq * 512]);
            }
        }
    };

    const int kbase = kc * 512;
    stage(kbase, 0);
    __syncthreads();  // drains vmcnt: buffer 0 ready

    int buf = 0;
    for (int it = 0; it < 16; ++it) {
        if (it < 15) stage(kbase + (it + 1) * 32, buf ^ 1);  // prefetch under compute

        const USHORT* Kb = Kl[buf];
        const USHORT* Vb = Vl[buf];

        // ---- SWAPPED scores: sacc[b][nt] = P^T tile (lane=q, row=key) ----
        f32x4 sacc[8][2];
#pragma unroll
        for (int b = 0; b < 8; ++b) { sacc[b][0] = fz4(); sacc[b][1] = fz4(); }
#pragma unroll
        for (int ks = 0; ks < 2; ++ks)
#pragma unroll
            for (int nt = 0; nt < 2; ++nt) {
                bf16x8 kf[8];
#pragma unroll
                for (int b = 0; b < 8; ++b)
                    kf[b] = ldbf8(&Kb[(b * 2 + ks) * 1024 + nt * 512 + lane * 8]);
#pragma unroll
                for (int b = 0; b < 8; ++b)
                    sacc[b][nt] = mfma16(kf[b], qf[b][ks], sacc[b][nt]);
            }

        // ---- softmax over batch axis (per-lane), normalize sacc IN PLACE ----
        // scores*scale ~ N(0,0.2^2): exp2 arg |x| < 2 even at 8 sigma.
#pragma unroll
        for (int nt = 0; nt < 2; ++nt)
#pragma unroll
            for (int r = 0; r < 4; ++r) {
                float e[8];
                float Z = 0.f;
#pragma unroll
                for (int b = 0; b < 8; ++b) {
                    // 0.125 (1/sqrt(64)) * log2(e)
                    e[b] = __builtin_amdgcn_exp2f(sacc[b][nt][r] * 0.1803368801f);
                    Z += e[b];
                }
                float inv = __builtin_amdgcn_rcpf(Z);
#pragma unroll
                for (int b = 0; b < 8; ++b)
                    sacc[b][nt][r] = e[b] * inv;
            }

        // ---- PV via ds_permute (cvt_pk pack; routing v10-verified) ----
#pragma unroll
        for (int b = 0; b < 8; ++b) {
            u32 w00 = cvtpk(sacc[b][0][0], sacc[b][0][1]);
            u32 w01 = cvtpk(sacc[b][0][2], sacc[b][0][3]);
            u32 w10 = cvtpk(sacc[b][1][0], sacc[b][1][1]);
            u32 w11 = cvtpk(sacc[b][1][2], sacc[b][1][3]);
            // send-side selects (routing verified in v10)
            u32 s0 = qodd ? w10 : w00, s1 = qodd ? w11 : w01;
            u32 s2 = qodd ? w00 : w10, s3 = qodd ? w01 : w11;
            u32 r0 = (u32)__builtin_amdgcn_ds_permute(idx01, (int)s0);
            u32 r1 = (u32)__builtin_amdgcn_ds_permute(idx01, (int)s1);
            u32 r2 = (u32)__builtin_amdgcn_ds_permute(idx23, (int)s2);
            u32 r3 = (u32)__builtin_amdgcn_ds_permute(idx23, (int)s3);
            // receive-side order: lanes quad<2 -> [r0,r1,r2,r3]; quad>=2 -> [r2,r3,r0,r1]
            union { u32 u[4]; bf16x8 v; } pu;
            pu.u[0] = qhi ? r2 : r0;
            pu.u[1] = qhi ? r3 : r1;
            pu.u[2] = qhi ? r0 : r2;
            pu.u[3] = qhi ? r1 : r3;
            bf16x8 pb = pu.v;   // B-layout: n=q=l16, k=key=quad*8+j

            bf16x8 vf[4];
#pragma unroll
            for (int nt = 0; nt < 4; ++nt)
                vf[nt] = ldbf8(&Vb[b * 2048 + nt * 512 + lane * 8]);  // A: m=d, k=key
#pragma unroll
            for (int nt = 0; nt < 4; ++nt)
                oacc[b][nt] = mfma16(vf[nt], pb, oacc[b][nt]);
        }

        __syncthreads();  // drains vmcnt (prefetch landed) + all LDS reads done
        buf ^= 1;
    }

    // ---- epilogue: full-128B-line stores via per-wave LDS transpose ----
    // oacc layout: q=l16 (col), d=nt*16+quad*4+r (row) -> ep[q][d] index below.
    // loop's final barrier done: all staging/LDS traffic finished -> Kl dead.
    USHORT* part = kc ? pt1 : pt0;
    USHORT* ep = ((USHORT*)Kl) + wv * (16 * 72);  // 4 x 2.25KB <= 64KB
#pragma unroll
    for (int b = 0; b < 8; ++b) {
#pragma unroll
        for (int nt = 0; nt < 4; ++nt)
#pragma unroll
            for (int r = 0; r < 4; ++r)
                ep[l16 * 72 + nt * 16 + quad * 4 + r] = f2bf(oacc[b][nt][r]);
        lds_fence();  // ds_write -> ds_read (wave-private)
#pragma unroll
        for (int half = 0; half < 2; ++half) {
            int row = half * 8 + (lane >> 3);
            int seg = lane & 7;
            u16x8 v = *(const u16x8*)&ep[row * 72 + seg * 8];
            *(u16x8*)(part + (size_t)((b << 10) + q0 + row) * 512 + h * 64 + seg * 8) = v;
        }
        lds_fence();  // WAR: reads drained before next b overwrites tile
    }
}

extern "C" void kernel_launch(void* const* d_in, const int* in_sizes, int n_in,
                              void* d_out, int out_size, void* d_ws, size_t ws_size,
                              hipStream_t stream) {
    const float* X = (const float*)d_in[0];     // (8,1024,512)
    const float* Wqkv = (const float*)d_in[1];  // (512,1536) — only cols 0..639 used
    const float* Wout = (const float*)d_in[2];  // (512,512)
    float* out = (float*)d_out;                 // (8,1024,512) fp32

    char* w = (char*)d_ws;
    USHORT* Xb  = (USHORT*)(w);              //  8,388,608 B (reused as pt0 later)
    USHORT* Wt1 = (USHORT*)(w + 8388608);    //    655,360 B  (640x512)
    USHORT* Wt3 = (USHORT*)(w + 9043968);    //    524,288 B  (512x512)
    USHORT* P   = (USHORT*)(w + 9568256);    // 10,485,760 B  (8192x640 bf16)
    USHORT* Vt  = (USHORT*)(w + 20054016);   //  8,388,608 B  (8x8x64x1024 bf16)
    USHORT* pt1 = (USHORT*)(w + 28442624);   //  8,388,608 B  partial ctx (kc=1)
    USHORT* pt0 = Xb;                        // Xb dead after GEMM1

    prep_kernel<<<4352, 256, 0, stream>>>(X, Wqkv, Wout, Xb, Wt1, Wt3);
    // P = Xb @ Wqkv[:, :640]
    gemm_bt<true><<<dim3(64, 5), 256, 0, stream>>>(Xb, Wt1, (void*)P, 8192, 640, 512);
    transpose_v<<<dim3(16, 8, 8), 256, 0, stream>>>(P, Vt);
    attn_kernel<<<256, 256, 0, stream>>>(P, Vt, pt0, pt1);
    // out = (pt0 + pt1) @ W_out  -- reduce2 fused into GEMM2's A-staging
    gemm_bt_sum2<<<dim3(64, 4), 256, 0, stream>>>(pt0, pt1, Wt3, out, 8192, 512, 512);
}

// Round 14
// 169.300 us; speedup vs baseline: 1.5489x; 1.0285x over previous
//
#include <hip/hip_runtime.h>

typedef __bf16 bf16x8 __attribute__((ext_vector_type(8)));
typedef float  f32x4  __attribute__((ext_vector_type(4)));
typedef unsigned short u16x8 __attribute__((ext_vector_type(8)));
typedef unsigned short USHORT;
typedef unsigned int   u32;

__device__ __forceinline__ USHORT f2bf(float f) {
    unsigned u = __float_as_uint(f);
    u += 0x7fffu + ((u >> 16) & 1u);
    return (USHORT)(u >> 16);
}

__device__ __forceinline__ float bf2f(USHORT v) {
    return __uint_as_float((unsigned)v << 16);
}

// HW packed f32->bf16 (RNE), 2 values in 1 op (T12 recipe; no builtin on gfx950)
__device__ __forceinline__ u32 cvtpk(float lo, float hi) {
    u32 r;
    asm("v_cvt_pk_bf16_f32 %0, %1, %2" : "=v"(r) : "v"(lo), "v"(hi));
    return r;
}

__device__ __forceinline__ f32x4 fz4() { f32x4 z = {0.f, 0.f, 0.f, 0.f}; return z; }

__device__ __forceinline__ bf16x8 ldbf8(const USHORT* p) { return *(const bf16x8*)p; }

__device__ __forceinline__ f32x4 mfma16(bf16x8 a, bf16x8 b, f32x4 c) {
    return __builtin_amdgcn_mfma_f32_16x16x32_bf16(a, b, c, 0, 0, 0);
}

// async global->LDS, 16B per lane; LDS dest is wave-uniform base + lane*16
__device__ __forceinline__ void gload_lds16(const void* g, void* s) {
    __builtin_amdgcn_global_load_lds(
        (const __attribute__((address_space(1))) unsigned int*)g,
        (__attribute__((address_space(3))) unsigned int*)s, 16, 0, 0);
}

// per-wave LDS ordering fence (epilogue only). sched_barrier per guide rule #18.
__device__ __forceinline__ void lds_fence() {
    asm volatile("s_waitcnt lgkmcnt(0)" ::: "memory");
    __builtin_amdgcn_sched_barrier(0);
}

// ---------------- merged prep: X fp32->bf16 + both W transposes ----------------
__global__ __launch_bounds__(256) void prep_kernel(const float* __restrict__ X,
                                                   const float* __restrict__ Wqkv,
                                                   const float* __restrict__ Wout,
                                                   USHORT* __restrict__ Xb,
                                                   USHORT* __restrict__ Wt1,
                                                   USHORT* __restrict__ Wt3) {
    int bid = blockIdx.x;
    if (bid < 2048) {
        int base = (bid * 256 + threadIdx.x) * 8;
        float4 a = *(const float4*)(X + base);
        float4 b = *(const float4*)(X + base + 4);
        u16x8 o;
        o[0] = f2bf(a.x); o[1] = f2bf(a.y); o[2] = f2bf(a.z); o[3] = f2bf(a.w);
        o[4] = f2bf(b.x); o[5] = f2bf(b.y); o[6] = f2bf(b.z); o[7] = f2bf(b.w);
        *(u16x8*)(Xb + base) = o;
    } else if (bid < 3328) {
        int t = (bid - 2048) * 256 + threadIdx.x;   // 0..327679 : 640x512
        int k = t & 511, n = t >> 9;
        Wt1[t] = f2bf(Wqkv[(size_t)k * 1536 + n]);
    } else {
        int t = (bid - 3328) * 256 + threadIdx.x;   // 0..262143 : 512x512
        int k = t & 511, n = t >> 9;
        Wt3[t] = f2bf(Wout[(size_t)k * 512 + n]);
    }
}

// ------------- bf16 GEMM, BM=128 x BN=64 (2 blocks/CU): C = A(MxK) * Bt^T -------
// r13 analysis: gemm1 (grid 320) and gemm2 (grid 256) ran the 128x128 m97
// structure at ~1 block/CU -> same 1-wave/SIMD latency exposure attn had, plus
// a 64-block tail on gemm1. BN=64 doubles the grid (640 / 512 blocks -> 2+/CU,
// __launch_bounds__(256,2)): two co-resident blocks overlap stage-drain with
// compute (m114 mechanism), tail shrinks 3x. Wave = 64m x 32n, acc[4][2],
// LDS 12KB, VGPR ~100 < 128 cap (no spills).
// SUM2: A = bf16(fp32(A0)+fp32(A1)) reg-staged (r13-proven path); else A0 via
// global_load_lds.
template <bool BF16OUT, bool SUM2>
__global__ __launch_bounds__(256, 2) void gemm_bn64(const USHORT* __restrict__ A0,
                                                    const USHORT* __restrict__ A1,
                                                    const USHORT* __restrict__ Bt,
                                                    void* __restrict__ Cv,
                                                    int M, int N, int K) {
    __shared__ __align__(16) USHORT Asm[128 * 32];
    __shared__ __align__(16) USHORT Bsm[64 * 32];
    const int tid = threadIdx.x;
    const int wv = tid >> 6, ln = tid & 63;
    const int l16 = ln & 15, quad = ln >> 4;
    const int m0 = blockIdx.x * 128, n0 = blockIdx.y * 64;
    const int wm = (wv >> 1) * 64, wn = (wv & 1) * 32;

    f32x4 acc[4][2];
#pragma unroll
    for (int i = 0; i < 4; ++i)
#pragma unroll
        for (int j = 0; j < 2; ++j) acc[i][j] = fz4();

    const int kTiles = K >> 5;
    for (int kt = 0; kt < kTiles; ++kt) {
        __syncthreads();  // prev iter's LDS reads done
#pragma unroll
        for (int i = 0; i < 2; ++i) {
            int cb = wv * 128 + i * 64;   // A chunk base (wave-uniform)
            int c = cb + ln;              // chunk: row=c>>2, 16B piece=(c&3)
            size_t aoff = (size_t)(m0 + (c >> 2)) * K + kt * 32 + (c & 3) * 8;
            if (SUM2) {
                u16x8 a0 = *(const u16x8*)(A0 + aoff);
                u16x8 a1 = *(const u16x8*)(A1 + aoff);
                union { u32 u[4]; u16x8 v; } s;
#pragma unroll
                for (int j = 0; j < 4; ++j)
                    s.u[j] = cvtpk(bf2f(a0[2 * j]) + bf2f(a1[2 * j]),
                                   bf2f(a0[2 * j + 1]) + bf2f(a1[2 * j + 1]));
                *(u16x8*)&Asm[c * 8] = s.v;   // linear 16B/lane: conflict-free
            } else {
                gload_lds16(A0 + aoff, &Asm[cb * 8]);
            }
        }
        {
            int cb = wv * 64;             // B chunk base: 64 rows x 4 pieces / 4 waves
            int c = cb + ln;
            gload_lds16(Bt + (size_t)(n0 + (c >> 2)) * K + kt * 32 + (c & 3) * 8,
                        &Bsm[cb * 8]);
        }
        __syncthreads();  // drains vmcnt (DMA) + lgkm (SUM2 ds_writes)

        bf16x8 af[4], bfr[2];
#pragma unroll
        for (int i = 0; i < 4; ++i)
            af[i] = ldbf8(&Asm[(wm + i * 16 + l16) * 32 + quad * 8]);
#pragma unroll
        for (int j = 0; j < 2; ++j)
            bfr[j] = ldbf8(&Bsm[(wn + j * 16 + l16) * 32 + quad * 8]);
#pragma unroll
        for (int i = 0; i < 4; ++i)
#pragma unroll
            for (int j = 0; j < 2; ++j)
                acc[i][j] = mfma16(af[i], bfr[j], acc[i][j]);
    }

    // epilogue: C/D layout col=lane&15, row=quad*4+reg (m89-verified)
#pragma unroll
    for (int i = 0; i < 4; ++i)
#pragma unroll
        for (int j = 0; j < 2; ++j)
#pragma unroll
            for (int r = 0; r < 4; ++r) {
                size_t row = m0 + wm + i * 16 + quad * 4 + r;
                size_t col = n0 + wn + j * 16 + l16;
                if (BF16OUT)
                    ((USHORT*)Cv)[row * N + col] = f2bf(acc[i][j][r]);
                else
                    ((float*)Cv)[row * N + col] = acc[i][j][r];
            }
}

// ---------------- V transpose: Vt[((b*8+h)*64+d)*1024+k] = P[(b*1024+k)*640+(h+2)*64+d]
__global__ __launch_bounds__(256) void transpose_v(const USHORT* __restrict__ P,
                                                   USHORT* __restrict__ Vt) {
    __shared__ __align__(16) USHORT T[64][72];
    const int t = threadIdx.x;
    const int k0 = blockIdx.x * 64;
    const int hh = blockIdx.y;
    const int b = blockIdx.z;
#pragma unroll
    for (int i = 0; i < 2; ++i) {
        int c = i * 256 + t;
        int kk = c >> 3, d8 = (c & 7) * 8;
        u16x8 v = *(const u16x8*)(P + (size_t)((b << 10) + k0 + kk) * 640 +
                                  (hh + 2) * 64 + d8);
        *(u16x8*)&T[kk][d8] = v;
    }
    __syncthreads();
#pragma unroll
    for (int i = 0; i < 2; ++i) {
        int d = (t >> 3) + i * 32;
        int kk0 = (t & 7) * 8;
        u16x8 v;
#pragma unroll
        for (int j = 0; j < 8; ++j) v[j] = T[kk0 + j][d];
        *(u16x8*)(Vt + (size_t)(((b << 3) + hh) * 64 + d) * 1024 + k0 + kk0) = v;
    }
}

// ---------------- fused attention v13 (r13-proven, 65us) -----------------------
// 256 blocks x 4 waves, 1 block/CU (512 regs/wave, no spills), double-buffered
// K/V staging, swapped-operand scores (mfma(K,Q) -> P^T, lane=q), per-lane
// batch-axis softmax, ds_permute PV (no LDS round-trip), cvt_pk pack,
// transposed full-line epilogue. UNCHANGED from round 13.
__global__ __launch_bounds__(256, 1) void attn_kernel(const USHORT* __restrict__ P,
                                                      const USHORT* __restrict__ Vt,
                                                      USHORT* __restrict__ pt0,
                                                      USHORT* __restrict__ pt1) {
    const int bid = blockIdx.x;
    const int g = bid & 15;                       // group (h,kc)
    const int h = g >> 1;
    const int kc = g & 1;                         // 0..1, 512 keys each
    const int qb = bid >> 4;                      // 0..15, 64 q each
    const int tid = threadIdx.x;
    const int wv = tid >> 6;                      // 0..3
    const int lane = tid & 63;
    const int l16 = lane & 15, quad = lane >> 4;
    const int q0 = qb * 64 + wv * 16;

    // Kl chunk map per (b,ks) 2KB region: chunk = half*64+s holds (key=half*16+(s&15), piece=s>>4)
    // Vl chunk map per (b)    4KB region: chunk = dq*32+s    holds (d=dq*16+(s&15),  piece=s>>4)
    __shared__ __align__(16) USHORT Kl[2][16384];   // 64KB (buf0 = epilogue scratch after loop)
    __shared__ __align__(16) USHORT Vl[2][16384];   // 64KB

    // ds_permute dest byte-indices (dest_lane*4), per-lane constants (v10-verified)
    const int qhalf = quad >> 1;                  // 0,0,1,1
    const bool qodd = (quad & 1) != 0;
    const bool qhi  = quad >= 2;
    const int idx01 = ((qodd ? (2 + qhalf) : qhalf) * 16 + l16) * 4;
    const int idx23 = ((qodd ? qhalf : (2 + qhalf)) * 16 + l16) * 4;

    // Q fragments: B-layout [n=l16 (q-row)][k=ks*32+quad*8+j] (64 VGPR, held all kernel)
    bf16x8 qf[8][2];
#pragma unroll
    for (int b = 0; b < 8; ++b)
#pragma unroll
        for (int ks = 0; ks < 2; ++ks)
            qf[b][ks] = ldbf8(P + (size_t)((b << 10) + q0 + l16) * 640 + h * 64 +
                              ks * 32 + quad * 8);

    // oacc TRANSPOSED: oacc[b][nt][r] = out[q=l16][d = nt*16 + quad*4 + r]
    f32x4 oacc[8][4];
#pragma unroll
    for (int b = 0; b < 8; ++b)
#pragma unroll
        for (int nt = 0; nt < 4; ++nt) oacc[b][nt] = fz4();

    // ---- staging: 64 gload_lds per it (16/wave); wv<2 -> K, wv>=2 -> V ----
    auto stage = [&](int k0s, int buf) {
        if (wv < 2) {
#pragma unroll
            for (int i = 0; i < 16; ++i) {
                int gg = wv * 16 + i;             // 0..31
                int b = gg >> 2, ks = (gg >> 1) & 1, half = gg & 1;
                gload_lds16(P + (size_t)((b << 10) + k0s + half * 16 + (lane & 15)) * 640 +
                                (h + 1) * 64 + ks * 32 + (lane >> 4) * 8,
                            &Kl[buf][(b * 2 + ks) * 1024 + half * 512]);
            }
        } else {
#pragma unroll
            for (int i = 0; i < 16; ++i) {
                int gg = (wv - 2) * 16 + i;       // 0..31
                int b = gg >> 2, dq = gg & 3;
                gload_lds16(Vt + (size_t)(((b << 3) + h) * 64 + dq * 16 + (lane & 15)) * 1024 +
                                k0s + (lane >> 4) * 8,
                            &Vl[buf][b * 2048 + dq * 512]);
            }
        }
    };

    const int kbase = kc * 512;
    stage(kbase, 0);
    __syncthreads();  // drains vmcnt: buffer 0 ready

    int buf = 0;
    for (int it = 0; it < 16; ++it) {
        if (it < 15) stage(kbase + (it + 1) * 32, buf ^ 1);  // prefetch under compute

        const USHORT* Kb = Kl[buf];
        const USHORT* Vb = Vl[buf];

        // ---- SWAPPED scores: sacc[b][nt] = P^T tile (lane=q, row=key) ----
        f32x4 sacc[8][2];
#pragma unroll
        for (int b = 0; b < 8; ++b) { sacc[b][0] = fz4(); sacc[b][1] = fz4(); }
#pragma unroll
        for (int ks = 0; ks < 2; ++ks)
#pragma unroll
            for (int nt = 0; nt < 2; ++nt) {
                bf16x8 kf[8];
#pragma unroll
                for (int b = 0; b < 8; ++b)
                    kf[b] = ldbf8(&Kb[(b * 2 + ks) * 1024 + nt * 512 + lane * 8]);
#pragma unroll
                for (int b = 0; b < 8; ++b)
                    sacc[b][nt] = mfma16(kf[b], qf[b][ks], sacc[b][nt]);
            }

        // ---- softmax over batch axis (per-lane), normalize sacc IN PLACE ----
        // scores*scale ~ N(0,0.2^2): exp2 arg |x| < 2 even at 8 sigma.
#pragma unroll
        for (int nt = 0; nt < 2; ++nt)
#pragma unroll
            for (int r = 0; r < 4; ++r) {
                float e[8];
                float Z = 0.f;
#pragma unroll
                for (int b = 0; b < 8; ++b) {
                    // 0.125 (1/sqrt(64)) * log2(e)
                    e[b] = __builtin_amdgcn_exp2f(sacc[b][nt][r] * 0.1803368801f);
                    Z += e[b];
                }
                float inv = __builtin_amdgcn_rcpf(Z);
#pragma unroll
                for (int b = 0; b < 8; ++b)
                    sacc[b][nt][r] = e[b] * inv;
            }

        // ---- PV via ds_permute (cvt_pk pack; routing v10-verified) ----
#pragma unroll
        for (int b = 0; b < 8; ++b) {
            u32 w00 = cvtpk(sacc[b][0][0], sacc[b][0][1]);
            u32 w01 = cvtpk(sacc[b][0][2], sacc[b][0][3]);
            u32 w10 = cvtpk(sacc[b][1][0], sacc[b][1][1]);
            u32 w11 = cvtpk(sacc[b][1][2], sacc[b][1][3]);
            // send-side selects (routing verified in v10)
            u32 s0 = qodd ? w10 : w00, s1 = qodd ? w11 : w01;
            u32 s2 = qodd ? w00 : w10, s3 = qodd ? w01 : w11;
            u32 r0 = (u32)__builtin_amdgcn_ds_permute(idx01, (int)s0);
            u32 r1 = (u32)__builtin_amdgcn_ds_permute(idx01, (int)s1);
            u32 r2 = (u32)__builtin_amdgcn_ds_permute(idx23, (int)s2);
            u32 r3 = (u32)__builtin_amdgcn_ds_permute(idx23, (int)s3);
            // receive-side order: lanes quad<2 -> [r0,r1,r2,r3]; quad>=2 -> [r2,r3,r0,r1]
            union { u32 u[4]; bf16x8 v; } pu;
            pu.u[0] = qhi ? r2 : r0;
            pu.u[1] = qhi ? r3 : r1;
            pu.u[2] = qhi ? r0 : r2;
            pu.u[3] = qhi ? r1 : r3;
            bf16x8 pb = pu.v;   // B-layout: n=q=l16, k=key=quad*8+j

            bf16x8 vf[4];
#pragma unroll
            for (int nt = 0; nt < 4; ++nt)
                vf[nt] = ldbf8(&Vb[b * 2048 + nt * 512 + lane * 8]);  // A: m=d, k=key
#pragma unroll
            for (int nt = 0; nt < 4; ++nt)
                oacc[b][nt] = mfma16(vf[nt], pb, oacc[b][nt]);
        }

        __syncthreads();  // drains vmcnt (prefetch landed) + all LDS reads done
        buf ^= 1;
    }

    // ---- epilogue: full-128B-line stores via per-wave LDS transpose ----
    // oacc layout: q=l16 (col), d=nt*16+quad*4+r (row) -> ep[q][d] index below.
    // loop's final barrier done: all staging/LDS traffic finished -> Kl dead.
    USHORT* part = kc ? pt1 : pt0;
    USHORT* ep = ((USHORT*)Kl) + wv * (16 * 72);  // 4 x 2.25KB <= 64KB
#pragma unroll
    for (int b = 0; b < 8; ++b) {
#pragma unroll
        for (int nt = 0; nt < 4; ++nt)
#pragma unroll
            for (int r = 0; r < 4; ++r)
                ep[l16 * 72 + nt * 16 + quad * 4 + r] = f2bf(oacc[b][nt][r]);
        lds_fence();  // ds_write -> ds_read (wave-private)
#pragma unroll
        for (int half = 0; half < 2; ++half) {
            int row = half * 8 + (lane >> 3);
            int seg = lane & 7;
            u16x8 v = *(const u16x8*)&ep[row * 72 + seg * 8];
            *(u16x8*)(part + (size_t)((b << 10) + q0 + row) * 512 + h * 64 + seg * 8) = v;
        }
        lds_fence();  // WAR: reads drained before next b overwrites tile
    }
}

extern "C" void kernel_launch(void* const* d_in, const int* in_sizes, int n_in,
                              void* d_out, int out_size, void* d_ws, size_t ws_size,
                              hipStream_t stream) {
    const float* X = (const float*)d_in[0];     // (8,1024,512)
    const float* Wqkv = (const float*)d_in[1];  // (512,1536) — only cols 0..639 used
    const float* Wout = (const float*)d_in[2];  // (512,512)
    float* out = (float*)d_out;                 // (8,1024,512) fp32

    char* w = (char*)d_ws;
    USHORT* Xb  = (USHORT*)(w);              //  8,388,608 B (reused as pt0 later)
    USHORT* Wt1 = (USHORT*)(w + 8388608);    //    655,360 B  (640x512)
    USHORT* Wt3 = (USHORT*)(w + 9043968);    //    524,288 B  (512x512)
    USHORT* P   = (USHORT*)(w + 9568256);    // 10,485,760 B  (8192x640 bf16)
    USHORT* Vt  = (USHORT*)(w + 20054016);   //  8,388,608 B  (8x8x64x1024 bf16)
    USHORT* pt1 = (USHORT*)(w + 28442624);   //  8,388,608 B  partial ctx (kc=1)
    USHORT* pt0 = Xb;                        // Xb dead after GEMM1

    prep_kernel<<<4352, 256, 0, stream>>>(X, Wqkv, Wout, Xb, Wt1, Wt3);
    // P = Xb @ Wqkv[:, :640]   (BN=64: 640 blocks, 2+/CU)
    gemm_bn64<true, false><<<dim3(64, 10), 256, 0, stream>>>(Xb, nullptr, Wt1,
                                                             (void*)P, 8192, 640, 512);
    transpose_v<<<dim3(16, 8, 8), 256, 0, stream>>>(P, Vt);
    attn_kernel<<<256, 256, 0, stream>>>(P, Vt, pt0, pt1);
    // out = (pt0 + pt1) @ W_out   (BN=64: 512 blocks, 2/CU; reduce fused)
    gemm_bn64<false, true><<<dim3(64, 8), 256, 0, stream>>>(pt0, pt1, Wt3,
                                                            (void*)out, 8192, 512, 512);
}

// Round 15
// 167.847 us; speedup vs baseline: 1.5623x; 1.0087x over previous
//
#include <hip/hip_runtime.h>

typedef __bf16 bf16x8 __attribute__((ext_vector_type(8)));
typedef float  f32x4  __attribute__((ext_vector_type(4)));
typedef unsigned short u16x8 __attribute__((ext_vector_type(8)));
typedef unsigned short USHORT;
typedef unsigned int   u32;

__device__ __forceinline__ USHORT f2bf(float f) {
    unsigned u = __float_as_uint(f);
    u += 0x7fffu + ((u >> 16) & 1u);
    return (USHORT)(u >> 16);
}

__device__ __forceinline__ float bf2f(USHORT v) {
    return __uint_as_float((unsigned)v << 16);
}

// HW packed f32->bf16 (RNE), 2 values in 1 op (T12 recipe; no builtin on gfx950)
__device__ __forceinline__ u32 cvtpk(float lo, float hi) {
    u32 r;
    asm("v_cvt_pk_bf16_f32 %0, %1, %2" : "=v"(r) : "v"(lo), "v"(hi));
    return r;
}

__device__ __forceinline__ f32x4 fz4() { f32x4 z = {0.f, 0.f, 0.f, 0.f}; return z; }

__device__ __forceinline__ bf16x8 ldbf8(const USHORT* p) { return *(const bf16x8*)p; }

__device__ __forceinline__ f32x4 mfma16(bf16x8 a, bf16x8 b, f32x4 c) {
    return __builtin_amdgcn_mfma_f32_16x16x32_bf16(a, b, c, 0, 0, 0);
}

// async global->LDS, 16B per lane; LDS dest is wave-uniform base + lane*16
__device__ __forceinline__ void gload_lds16(const void* g, void* s) {
    __builtin_amdgcn_global_load_lds(
        (const __attribute__((address_space(1))) unsigned int*)g,
        (__attribute__((address_space(3))) unsigned int*)s, 16, 0, 0);
}

// per-wave LDS ordering fence (epilogue only). sched_barrier per guide rule #18.
__device__ __forceinline__ void lds_fence() {
    asm volatile("s_waitcnt lgkmcnt(0)" ::: "memory");
    __builtin_amdgcn_sched_barrier(0);
}

// ---------------- merged prep: X fp32->bf16 + both W transposes ----------------
__global__ __launch_bounds__(256) void prep_kernel(const float* __restrict__ X,
                                                   const float* __restrict__ Wqkv,
                                                   const float* __restrict__ Wout,
                                                   USHORT* __restrict__ Xb,
                                                   USHORT* __restrict__ Wt1,
                                                   USHORT* __restrict__ Wt3) {
    int bid = blockIdx.x;
    if (bid < 2048) {
        int base = (bid * 256 + threadIdx.x) * 8;
        float4 a = *(const float4*)(X + base);
        float4 b = *(const float4*)(X + base + 4);
        u16x8 o;
        o[0] = f2bf(a.x); o[1] = f2bf(a.y); o[2] = f2bf(a.z); o[3] = f2bf(a.w);
        o[4] = f2bf(b.x); o[5] = f2bf(b.y); o[6] = f2bf(b.z); o[7] = f2bf(b.w);
        *(u16x8*)(Xb + base) = o;
    } else if (bid < 3328) {
        int t = (bid - 2048) * 256 + threadIdx.x;   // 0..327679 : 640x512
        int k = t & 511, n = t >> 9;
        Wt1[t] = f2bf(Wqkv[(size_t)k * 1536 + n]);
    } else {
        int t = (bid - 3328) * 256 + threadIdx.x;   // 0..262143 : 512x512
        int k = t & 511, n = t >> 9;
        Wt3[t] = f2bf(Wout[(size_t)k * 512 + n]);
    }
}

// ------------- bf16 GEMM, BM=128 x BN=64 (2 blocks/CU): C = A(MxK) * Bt^T -------
// r14-proven (total 174->169). Wave = 64m x 32n, acc[4][2], 2 blocks/CU via
// __launch_bounds__(256,2); SUM2 reg-stages A = bf16(fp32(A0)+fp32(A1)).
// NEW (r15): WRITE_VT fuses the transpose_v kernel into the epilogue. For
// blockIdx.y>=2 the block's 128k x 64d tile IS one (batch,head) V tile:
// per-wave LDS transpose ([32 d][72] stride, same full-line pattern as the
// attn epilogue; uniform 8 touches/bank at the b128 floor) emits Vt directly.
// Values bit-identical to transpose_v's (f2bf(acc) both paths). Removes a
// 1024-block kernel + launch gap + 34MB of P->Vt round-trip traffic.
template <bool BF16OUT, bool SUM2, bool WRITE_VT>
__global__ __launch_bounds__(256, 2) void gemm_bn64(const USHORT* __restrict__ A0,
                                                    const USHORT* __restrict__ A1,
                                                    const USHORT* __restrict__ Bt,
                                                    void* __restrict__ Cv,
                                                    USHORT* __restrict__ Vt,
                                                    int M, int N, int K) {
    __shared__ __align__(16) USHORT Asm[128 * 32];
    __shared__ __align__(16) USHORT Bsm[64 * 32];
    __shared__ __align__(16) USHORT Vtile[WRITE_VT ? 4 * 2304 : 4];  // 18KB when used
    const int tid = threadIdx.x;
    const int wv = tid >> 6, ln = tid & 63;
    const int l16 = ln & 15, quad = ln >> 4;
    const int m0 = blockIdx.x * 128, n0 = blockIdx.y * 64;
    const int wm = (wv >> 1) * 64, wn = (wv & 1) * 32;

    f32x4 acc[4][2];
#pragma unroll
    for (int i = 0; i < 4; ++i)
#pragma unroll
        for (int j = 0; j < 2; ++j) acc[i][j] = fz4();

    const int kTiles = K >> 5;
    for (int kt = 0; kt < kTiles; ++kt) {
        __syncthreads();  // prev iter's LDS reads done
#pragma unroll
        for (int i = 0; i < 2; ++i) {
            int cb = wv * 128 + i * 64;   // A chunk base (wave-uniform)
            int c = cb + ln;              // chunk: row=c>>2, 16B piece=(c&3)
            size_t aoff = (size_t)(m0 + (c >> 2)) * K + kt * 32 + (c & 3) * 8;
            if (SUM2) {
                u16x8 a0 = *(const u16x8*)(A0 + aoff);
                u16x8 a1 = *(const u16x8*)(A1 + aoff);
                union { u32 u[4]; u16x8 v; } s;
#pragma unroll
                for (int j = 0; j < 4; ++j)
                    s.u[j] = cvtpk(bf2f(a0[2 * j]) + bf2f(a1[2 * j]),
                                   bf2f(a0[2 * j + 1]) + bf2f(a1[2 * j + 1]));
                *(u16x8*)&Asm[c * 8] = s.v;   // linear 16B/lane: conflict-free
            } else {
                gload_lds16(A0 + aoff, &Asm[cb * 8]);
            }
        }
        {
            int cb = wv * 64;             // B chunk base: 64 rows x 4 pieces / 4 waves
            int c = cb + ln;
            gload_lds16(Bt + (size_t)(n0 + (c >> 2)) * K + kt * 32 + (c & 3) * 8,
                        &Bsm[cb * 8]);
        }
        __syncthreads();  // drains vmcnt (DMA) + lgkm (SUM2 ds_writes)

        bf16x8 af[4], bfr[2];
#pragma unroll
        for (int i = 0; i < 4; ++i)
            af[i] = ldbf8(&Asm[(wm + i * 16 + l16) * 32 + quad * 8]);
#pragma unroll
        for (int j = 0; j < 2; ++j)
            bfr[j] = ldbf8(&Bsm[(wn + j * 16 + l16) * 32 + quad * 8]);
#pragma unroll
        for (int i = 0; i < 4; ++i)
#pragma unroll
            for (int j = 0; j < 2; ++j)
                acc[i][j] = mfma16(af[i], bfr[j], acc[i][j]);
    }

    // epilogue: C/D layout col=lane&15, row=quad*4+reg (m89-verified)
#pragma unroll
    for (int i = 0; i < 4; ++i)
#pragma unroll
        for (int j = 0; j < 2; ++j)
#pragma unroll
            for (int r = 0; r < 4; ++r) {
                size_t row = m0 + wm + i * 16 + quad * 4 + r;
                size_t col = n0 + wn + j * 16 + l16;
                if (BF16OUT)
                    ((USHORT*)Cv)[row * N + col] = f2bf(acc[i][j][r]);
                else
                    ((float*)Cv)[row * N + col] = acc[i][j][r];
            }

    // fused V-transpose epilogue: this block's tile is (batch b, head hh, d, k)
    if constexpr (WRITE_VT) {
        if (blockIdx.y >= 2) {            // cols >=128 are the V region
            const int hh = blockIdx.y - 2;            // head 0..7
            const int b = m0 >> 10;                   // batch
            const int kb = (m0 & 1023) + wm;          // wave's first k row
            USHORT* tp = &Vtile[wv * 2304];           // [32 d][72] per wave
            // write transposed: tile[d_local][k_local]
#pragma unroll
            for (int i = 0; i < 4; ++i)
#pragma unroll
                for (int j = 0; j < 2; ++j)
#pragma unroll
                    for (int r = 0; r < 4; ++r)
                        tp[(j * 16 + l16) * 72 + i * 16 + quad * 4 + r] =
                            f2bf(acc[i][j][r]);
            lds_fence();  // ds_write -> ds_read (wave-private tile)
            // read full 16B k-runs, store full-line contiguous Vt rows
#pragma unroll
            for (int t = 0; t < 4; ++t) {
                int idx = t * 64 + ln;
                int dl = idx >> 3, seg = idx & 7;
                u16x8 v = *(const u16x8*)&tp[dl * 72 + seg * 8];
                *(u16x8*)(Vt + ((size_t)(((b << 3) + hh) << 6) + wn + dl) * 1024 +
                          kb + seg * 8) = v;
            }
        }
    }
}

// ---------------- fused attention v13 (r13/r14-proven, ~65us) ------------------
// 256 blocks x 4 waves, 1 block/CU (512 regs/wave, no spills), double-buffered
// K/V staging, swapped-operand scores (mfma(K,Q) -> P^T, lane=q), per-lane
// batch-axis softmax, ds_permute PV (no LDS round-trip), cvt_pk pack,
// transposed full-line epilogue. UNCHANGED.
__global__ __launch_bounds__(256, 1) void attn_kernel(const USHORT* __restrict__ P,
                                                      const USHORT* __restrict__ Vt,
                                                      USHORT* __restrict__ pt0,
                                                      USHORT* __restrict__ pt1) {
    const int bid = blockIdx.x;
    const int g = bid & 15;                       // group (h,kc)
    const int h = g >> 1;
    const int kc = g & 1;                         // 0..1, 512 keys each
    const int qb = bid >> 4;                      // 0..15, 64 q each
    const int tid = threadIdx.x;
    const int wv = tid >> 6;                      // 0..3
    const int lane = tid & 63;
    const int l16 = lane & 15, quad = lane >> 4;
    const int q0 = qb * 64 + wv * 16;

    // Kl chunk map per (b,ks) 2KB region: chunk = half*64+s holds (key=half*16+(s&15), piece=s>>4)
    // Vl chunk map per (b)    4KB region: chunk = dq*32+s    holds (d=dq*16+(s&15),  piece=s>>4)
    __shared__ __align__(16) USHORT Kl[2][16384];   // 64KB (buf0 = epilogue scratch after loop)
    __shared__ __align__(16) USHORT Vl[2][16384];   // 64KB

    // ds_permute dest byte-indices (dest_lane*4), per-lane constants (v10-verified)
    const int qhalf = quad >> 1;                  // 0,0,1,1
    const bool qodd = (quad & 1) != 0;
    const bool qhi  = quad >= 2;
    const int idx01 = ((qodd ? (2 + qhalf) : qhalf) * 16 + l16) * 4;
    const int idx23 = ((qodd ? qhalf : (2 + qhalf)) * 16 + l16) * 4;

    // Q fragments: B-layout [n=l16 (q-row)][k=ks*32+quad*8+j] (64 VGPR, held all kernel)
    bf16x8 qf[8][2];
#pragma unroll
    for (int b = 0; b < 8; ++b)
#pragma unroll
        for (int ks = 0; ks < 2; ++ks)
            qf[b][ks] = ldbf8(P + (size_t)((b << 10) + q0 + l16) * 640 + h * 64 +
                              ks * 32 + quad * 8);

    // oacc TRANSPOSED: oacc[b][nt][r] = out[q=l16][d = nt*16 + quad*4 + r]
    f32x4 oacc[8][4];
#pragma unroll
    for (int b = 0; b < 8; ++b)
#pragma unroll
        for (int nt = 0; nt < 4; ++nt) oacc[b][nt] = fz4();

    // ---- staging: 64 gload_lds per it (16/wave); wv<2 -> K, wv>=2 -> V ----
    auto stage = [&](int k0s, int buf) {
        if (wv < 2) {
#pragma unroll
            for (int i = 0; i < 16; ++i) {
                int gg = wv * 16 + i;             // 0..31
                int b = gg >> 2, ks = (gg >> 1) & 1, half = gg & 1;
                gload_lds16(P + (size_t)((b << 10) + k0s + half * 16 + (lane & 15)) * 640 +
                                (h + 1) * 64 + ks * 32 + (lane >> 4) * 8,
                            &Kl[buf][(b * 2 + ks) * 1024 + half * 512]);
            }
        } else {
#pragma unroll
            for (int i = 0; i < 16; ++i) {
                int gg = (wv - 2) * 16 + i;       // 0..31
                int b = gg >> 2, dq = gg & 3;
                gload_lds16(Vt + (size_t)(((b << 3) + h) * 64 + dq * 16 + (lane & 15)) * 1024 +
                                k0s + (lane >> 4) * 8,
                            &Vl[buf][b * 2048 + dq * 512]);
            }
        }
    };

    const int kbase = kc * 512;
    stage(kbase, 0);
    __syncthreads();  // drains vmcnt: buffer 0 ready

    int buf = 0;
    for (int it = 0; it < 16; ++it) {
        if (it < 15) stage(kbase + (it + 1) * 32, buf ^ 1);  // prefetch under compute

        const USHORT* Kb = Kl[buf];
        const USHORT* Vb = Vl[buf];

        // ---- SWAPPED scores: sacc[b][nt] = P^T tile (lane=q, row=key) ----
        f32x4 sacc[8][2];
#pragma unroll
        for (int b = 0; b < 8; ++b) { sacc[b][0] = fz4(); sacc[b][1] = fz4(); }
#pragma unroll
        for (int ks = 0; ks < 2; ++ks)
#pragma unroll
            for (int nt = 0; nt < 2; ++nt) {
                bf16x8 kf[8];
#pragma unroll
                for (int b = 0; b < 8; ++b)
                    kf[b] = ldbf8(&Kb[(b * 2 + ks) * 1024 + nt * 512 + lane * 8]);
#pragma unroll
                for (int b = 0; b < 8; ++b)
                    sacc[b][nt] = mfma16(kf[b], qf[b][ks], sacc[b][nt]);
            }

        // ---- softmax over batch axis (per-lane), normalize sacc IN PLACE ----
        // scores*scale ~ N(0,0.2^2): exp2 arg |x| < 2 even at 8 sigma.
#pragma unroll
        for (int nt = 0; nt < 2; ++nt)
#pragma unroll
            for (int r = 0; r < 4; ++r) {
                float e[8];
                float Z = 0.f;
#pragma unroll
                for (int b = 0; b < 8; ++b) {
                    // 0.125 (1/sqrt(64)) * log2(e)
                    e[b] = __builtin_amdgcn_exp2f(sacc[b][nt][r] * 0.1803368801f);
                    Z += e[b];
                }
                float inv = __builtin_amdgcn_rcpf(Z);
#pragma unroll
                for (int b = 0; b < 8; ++b)
                    sacc[b][nt][r] = e[b] * inv;
            }

        // ---- PV via ds_permute (cvt_pk pack; routing v10-verified) ----
#pragma unroll
        for (int b = 0; b < 8; ++b) {
            u32 w00 = cvtpk(sacc[b][0][0], sacc[b][0][1]);
            u32 w01 = cvtpk(sacc[b][0][2], sacc[b][0][3]);
            u32 w10 = cvtpk(sacc[b][1][0], sacc[b][1][1]);
            u32 w11 = cvtpk(sacc[b][1][2], sacc[b][1][3]);
            // send-side selects (routing verified in v10)
            u32 s0 = qodd ? w10 : w00, s1 = qodd ? w11 : w01;
            u32 s2 = qodd ? w00 : w10, s3 = qodd ? w01 : w11;
            u32 r0 = (u32)__builtin_amdgcn_ds_permute(idx01, (int)s0);
            u32 r1 = (u32)__builtin_amdgcn_ds_permute(idx01, (int)s1);
            u32 r2 = (u32)__builtin_amdgcn_ds_permute(idx23, (int)s2);
            u32 r3 = (u32)__builtin_amdgcn_ds_permute(idx23, (int)s3);
            // receive-side order: lanes quad<2 -> [r0,r1,r2,r3]; quad>=2 -> [r2,r3,r0,r1]
            union { u32 u[4]; bf16x8 v; } pu;
            pu.u[0] = qhi ? r2 : r0;
            pu.u[1] = qhi ? r3 : r1;
            pu.u[2] = qhi ? r0 : r2;
            pu.u[3] = qhi ? r1 : r3;
            bf16x8 pb = pu.v;   // B-layout: n=q=l16, k=key=quad*8+j

            bf16x8 vf[4];
#pragma unroll
            for (int nt = 0; nt < 4; ++nt)
                vf[nt] = ldbf8(&Vb[b * 2048 + nt * 512 + lane * 8]);  // A: m=d, k=key
#pragma unroll
            for (int nt = 0; nt < 4; ++nt)
                oacc[b][nt] = mfma16(vf[nt], pb, oacc[b][nt]);
        }

        __syncthreads();  // drains vmcnt (prefetch landed) + all LDS reads done
        buf ^= 1;
    }

    // ---- epilogue: full-128B-line stores via per-wave LDS transpose ----
    // oacc layout: q=l16 (col), d=nt*16+quad*4+r (row) -> ep[q][d] index below.
    // loop's final barrier done: all staging/LDS traffic finished -> Kl dead.
    USHORT* part = kc ? pt1 : pt0;
    USHORT* ep = ((USHORT*)Kl) + wv * (16 * 72);  // 4 x 2.25KB <= 64KB
#pragma unroll
    for (int b = 0; b < 8; ++b) {
#pragma unroll
        for (int nt = 0; nt < 4; ++nt)
#pragma unroll
            for (int r = 0; r < 4; ++r)
                ep[l16 * 72 + nt * 16 + quad * 4 + r] = f2bf(oacc[b][nt][r]);
        lds_fence();  // ds_write -> ds_read (wave-private)
#pragma unroll
        for (int half = 0; half < 2; ++half) {
            int row = half * 8 + (lane >> 3);
            int seg = lane & 7;
            u16x8 v = *(const u16x8*)&ep[row * 72 + seg * 8];
            *(u16x8*)(part + (size_t)((b << 10) + q0 + row) * 512 + h * 64 + seg * 8) = v;
        }
        lds_fence();  // WAR: reads drained before next b overwrites tile
    }
}

extern "C" void kernel_launch(void* const* d_in, const int* in_sizes, int n_in,
                              void* d_out, int out_size, void* d_ws, size_t ws_size,
                              hipStream_t stream) {
    const float* X = (const float*)d_in[0];     // (8,1024,512)
    const float* Wqkv = (const float*)d_in[1];  // (512,1536) — only cols 0..639 used
    const float* Wout = (const float*)d_in[2];  // (512,512)
    float* out = (float*)d_out;                 // (8,1024,512) fp32

    char* w = (char*)d_ws;
    USHORT* Xb  = (USHORT*)(w);              //  8,388,608 B (reused as pt0 later)
    USHORT* Wt1 = (USHORT*)(w + 8388608);    //    655,360 B  (640x512)
    USHORT* Wt3 = (USHORT*)(w + 9043968);    //    524,288 B  (512x512)
    USHORT* P   = (USHORT*)(w + 9568256);    // 10,485,760 B  (8192x640 bf16)
    USHORT* Vt  = (USHORT*)(w + 20054016);   //  8,388,608 B  (8x8x64x1024 bf16)
    USHORT* pt1 = (USHORT*)(w + 28442624);   //  8,388,608 B  partial ctx (kc=1)
    USHORT* pt0 = Xb;                        // Xb dead after GEMM1

    prep_kernel<<<4352, 256, 0, stream>>>(X, Wqkv, Wout, Xb, Wt1, Wt3);
    // P = Xb @ Wqkv[:, :640]; V tiles transposed into Vt in the same epilogue
    gemm_bn64<true, false, true><<<dim3(64, 10), 256, 0, stream>>>(
        Xb, nullptr, Wt1, (void*)P, Vt, 8192, 640, 512);
    attn_kernel<<<256, 256, 0, stream>>>(P, Vt, pt0, pt1);
    // out = (pt0 + pt1) @ W_out   (reduce fused into A-staging)
    gemm_bn64<false, true, false><<<dim3(64, 8), 256, 0, stream>>>(
        pt0, pt1, Wt3, (void*)out, nullptr, 8192, 512, 512);
}